// Round 2
// baseline (2627.837 us; speedup 1.0000x reference)
//
#include <hip/hip_runtime.h>
#include <hip/hip_bf16.h>

// Problem constants
#define BB 2
#define SS 1024
#define DD 1024
#define NH 16
#define DH 64
#define MM 8
#define RR 128
#define NN 256
#define NT (BB*SS)          // 2048 tokens

using bf16 = __hip_bfloat16;

__device__ __forceinline__ float ldf(const float* p, int i) { return p[i]; }
__device__ __forceinline__ float ldf(const bf16* p, int i) { return __bfloat162float(p[i]); }
__device__ __forceinline__ void stf(float* p, int i, float v) { p[i] = v; }
__device__ __forceinline__ void stf(bf16* p, int i, float v) { p[i] = __float2bfloat16(v); }

// Generic tiled GEMM: C[M,N] = A[M,K] @ B[K,N].
// BM=BN=64, BK=16, 256 threads, 4x4 per thread. M = gridDim.y*64.
// BMODE==0: B row-major [K,N] with ldb.
// BMODE==1: B is qk_f-style [8, K, 128]: B[k][n] = Bp[(n>>7)*K*128 + k*128 + (n&127)].
template <typename TA, typename TB, typename TC, int BMODE>
__global__ void gemm_tile(const TA* __restrict__ A, const TB* __restrict__ B,
                          TC* __restrict__ C, int Ndim, int Kdim,
                          int lda, int ldb, int ldc) {
    __shared__ float As[16][64];
    __shared__ float Bs[16][64];
    const int tid = threadIdx.x;
    const int bx = blockIdx.x;   // n tile
    const int by = blockIdx.y;   // m tile
    const int tx = tid & 15;     // 16 col-threads
    const int ty = tid >> 4;     // 16 row-threads
    const int m0 = by * 64 + ty * 4;
    const int n0 = bx * 64 + tx * 4;

    float acc[4][4];
#pragma unroll
    for (int i = 0; i < 4; ++i)
#pragma unroll
        for (int j = 0; j < 4; ++j) acc[i][j] = 0.f;

    for (int k0 = 0; k0 < Kdim; k0 += 16) {
        // Load A tile 64x16 (store transposed: As[k][m])
#pragma unroll
        for (int i = 0; i < 4; ++i) {
            int e = tid + i * 256;
            int m = e >> 4, k = e & 15;
            As[k][m] = ldf(A, (by * 64 + m) * lda + k0 + k);
        }
        // Load B tile 16x64
#pragma unroll
        for (int i = 0; i < 4; ++i) {
            int e = tid + i * 256;
            int k = e >> 6, n = e & 63;
            int gn = bx * 64 + n;
            int gk = k0 + k;
            float v;
            if (BMODE == 0) v = ldf(B, gk * ldb + gn);
            else            v = ldf(B, (gn >> 7) * (Kdim * 128) + gk * 128 + (gn & 127));
            Bs[k][n] = v;
        }
        __syncthreads();
#pragma unroll
        for (int k = 0; k < 16; ++k) {
            float a[4], b[4];
#pragma unroll
            for (int i = 0; i < 4; ++i) a[i] = As[k][ty * 4 + i];
#pragma unroll
            for (int j = 0; j < 4; ++j) b[j] = Bs[k][tx * 4 + j];
#pragma unroll
            for (int i = 0; i < 4; ++i)
#pragma unroll
                for (int j = 0; j < 4; ++j) acc[i][j] += a[i] * b[j];
        }
        __syncthreads();
    }
#pragma unroll
    for (int i = 0; i < 4; ++i)
#pragma unroll
        for (int j = 0; j < 4; ++j)
            stf(C, (m0 + i) * ldc + n0 + j, acc[i][j]);
}

// Softmax over 256 logits, group-sum in chunks of 32, normalize -> g[t][8]
__global__ void gate_kernel(const float* __restrict__ logits, float* __restrict__ g) {
    const int t = blockIdx.x;
    const int n = threadIdx.x;   // 256
    __shared__ float red[256];
    __shared__ float probs[256];

    float v = logits[t * NN + n];
    red[n] = v;
    __syncthreads();
    for (int s = 128; s > 0; s >>= 1) {
        if (n < s) red[n] = fmaxf(red[n], red[n + s]);
        __syncthreads();
    }
    float mx = red[0];
    __syncthreads();
    float e = expf(v - mx);
    probs[n] = e;
    red[n] = e;
    __syncthreads();
    for (int s = 128; s > 0; s >>= 1) {
        if (n < s) red[n] += red[n + s];
        __syncthreads();
    }
    float denom = red[0];
    __syncthreads();
    if (n < 8) {
        float s = 0.f;
#pragma unroll
        for (int i = 0; i < 32; ++i) s += probs[n * 32 + i];
        red[n] = s / denom;
    }
    __syncthreads();
    if (n == 0) {
        float tot = 0.f;
#pragma unroll
        for (int m = 0; m < 8; ++m) tot += red[m];
        float inv = 1.0f / (tot + 1e-8f);
#pragma unroll
        for (int m = 0; m < 8; ++m) g[t * 8 + m] = red[m] * inv;
    }
}

// h[t][r] = sum_m allh[t][m*128+r] * g[t][m]
__global__ void combine_h(const float* __restrict__ allh, const float* __restrict__ g,
                          float* __restrict__ h) {
    int idx = blockIdx.x * blockDim.x + threadIdx.x;   // t*128+r
    int t = idx >> 7, r = idx & 127;
    float acc = 0.f;
#pragma unroll
    for (int m = 0; m < 8; ++m)
        acc += allh[t * 1024 + m * 128 + r] * g[t * 8 + m];
    h[idx] = acc;
}

// pre[t][m*128+r] = h[t][r] * g[t][m]
__global__ void make_pre(const float* __restrict__ h, const float* __restrict__ g,
                         float* __restrict__ pre) {
    int idx = blockIdx.x * blockDim.x + threadIdx.x;   // t*1024 + m*128 + r
    int t = idx >> 10;
    int mr = idx & 1023;
    int m = mr >> 7, r = mr & 127;
    pre[idx] = h[t * 128 + r] * g[t * 8 + m];
}

// Causal attention, one block (256 thr) per (b,h,sq) row. Q/K/V stored bf16.
__global__ void attn_kernel(const bf16* __restrict__ Q, const bf16* __restrict__ K,
                            const bf16* __restrict__ V, float* __restrict__ out) {
    const int sq = blockIdx.x;
    const int bh = blockIdx.y;
    const int b = bh >> 4;
    const int h = bh & 15;
    const int tid = threadIdx.x;

    __shared__ float q[DH];
    __shared__ float sc[SS];
    __shared__ float red[256];

    const int rowbase = (b * SS + sq) * DD + h * DH;
    if (tid < DH) q[tid] = __bfloat162float(Q[rowbase + tid]);
    __syncthreads();

    const float scale = 0.125f;   // 1/sqrt(64)
    const int kvbase = b * SS * DD + h * DH;
    for (int t = tid; t <= sq; t += 256) {
        const bf16* kr = K + kvbase + t * DD;
        float dot = 0.f;
#pragma unroll
        for (int d = 0; d < DH; ++d) dot += q[d] * __bfloat162float(kr[d]);
        sc[t] = dot * scale;
    }
    __syncthreads();

    // max
    float lmax = -1e30f;
    for (int t = tid; t <= sq; t += 256) lmax = fmaxf(lmax, sc[t]);
    red[tid] = lmax;
    __syncthreads();
    for (int s = 128; s > 0; s >>= 1) {
        if (tid < s) red[tid] = fmaxf(red[tid], red[tid + s]);
        __syncthreads();
    }
    float mx = red[0];
    __syncthreads();
    // exp + sum
    float lsum = 0.f;
    for (int t = tid; t <= sq; t += 256) {
        float e = expf(sc[t] - mx);
        sc[t] = e;
        lsum += e;
    }
    red[tid] = lsum;
    __syncthreads();
    for (int s = 128; s > 0; s >>= 1) {
        if (tid < s) red[tid] += red[tid + s];
        __syncthreads();
    }
    float denom = red[0];
    __syncthreads();

    // out[d] = sum_t p[t]*V[t][d]
    const int d = tid & 63;
    const int gch = tid >> 6;   // 4 groups over t
    float acc = 0.f;
    for (int t = gch; t <= sq; t += 4)
        acc += sc[t] * __bfloat162float(V[kvbase + t * DD + d]);
    red[tid] = acc;
    __syncthreads();
    if (gch == 0) {
        float o = (red[d] + red[64 + d] + red[128 + d] + red[192 + d]) / denom;
        out[rowbase + d] = o;
    }
}

extern "C" void kernel_launch(void* const* d_in, const int* in_sizes, int n_in,
                              void* d_out, int out_size, void* d_ws, size_t ws_size,
                              hipStream_t stream) {
    // Reference dtypes are float32 for ALL inputs and the output.
    const float* x    = (const float*)d_in[0];
    const float* qk_f = (const float*)d_in[1];
    const float* qk_r = (const float*)d_in[2];
    const float* v_f  = (const float*)d_in[3];
    const float* v_r  = (const float*)d_in[4];
    const float* Wg_q = (const float*)d_in[5];
    const float* Wg_k = (const float*)d_in[6];
    const float* Wg_v = (const float*)d_in[7];
    const float* W_O  = (const float*)d_in[8];
    float* out = (float*)d_out;

    // Workspace layout (23.2 MB):
    //   buf0 : f32 [2048,1024]  (logits -> all_h -> pre -> attn_out), 8 MB
    //   g*   : f32 [2048,8] x3
    //   h*   : f32 [2048,128] x3, 3 MB
    //   QKV  : bf16 [2048,1024] x3, 12 MB
    float* ws = (float*)d_ws;
    float* buf0 = ws;
    float* gQ   = buf0 + NT * DD;
    float* gK   = gQ + NT * MM;
    float* gV   = gK + NT * MM;
    float* hQ   = gV + NT * MM;
    float* hK   = hQ + NT * RR;
    float* hV   = hK + NT * RR;
    bf16* Qb = (bf16*)(hV + NT * RR);
    bf16* Kb = Qb + NT * DD;
    bf16* Vb = Kb + NT * DD;

    dim3 blk(256);

    // 1) Gates
    const float* Wgs[3] = {Wg_q, Wg_k, Wg_v};
    float* gs[3] = {gQ, gK, gV};
    for (int i = 0; i < 3; ++i) {
        gemm_tile<float, float, float, 0><<<dim3(NN / 64, NT / 64), blk, 0, stream>>>(
            x, Wgs[i], buf0, NN, DD, DD, NN, NN);
        gate_kernel<<<NT, 256, 0, stream>>>(buf0, gs[i]);
    }

    // 2) all_h (qk shared by Q and K), then h
    gemm_tile<float, float, float, 1><<<dim3(DD / 64, NT / 64), blk, 0, stream>>>(
        x, qk_f, buf0, MM * RR, DD, DD, 0, MM * RR);
    combine_h<<<NT * RR / 256, 256, 0, stream>>>(buf0, gQ, hQ);
    combine_h<<<NT * RR / 256, 256, 0, stream>>>(buf0, gK, hK);
    gemm_tile<float, float, float, 1><<<dim3(DD / 64, NT / 64), blk, 0, stream>>>(
        x, v_f, buf0, MM * RR, DD, DD, 0, MM * RR);
    combine_h<<<NT * RR / 256, 256, 0, stream>>>(buf0, gV, hV);

    // 3) restore -> Q, K, V (bf16) ; qk_r/v_r flatten to row-major [M*R, D]
    make_pre<<<NT * DD / 256, 256, 0, stream>>>(hQ, gQ, buf0);
    gemm_tile<float, float, bf16, 0><<<dim3(DD / 64, NT / 64), blk, 0, stream>>>(
        buf0, qk_r, Qb, DD, MM * RR, MM * RR, DD, DD);
    make_pre<<<NT * DD / 256, 256, 0, stream>>>(hK, gK, buf0);
    gemm_tile<float, float, bf16, 0><<<dim3(DD / 64, NT / 64), blk, 0, stream>>>(
        buf0, qk_r, Kb, DD, MM * RR, MM * RR, DD, DD);
    make_pre<<<NT * DD / 256, 256, 0, stream>>>(hV, gV, buf0);
    gemm_tile<float, float, bf16, 0><<<dim3(DD / 64, NT / 64), blk, 0, stream>>>(
        buf0, v_r, Vb, DD, MM * RR, MM * RR, DD, DD);

    // 4) causal attention -> buf0 (attn_out, [B,S,D] head-merged layout)
    attn_kernel<<<dim3(SS, BB * NH), 256, 0, stream>>>(Qb, Kb, Vb, buf0);

    // 5) out = attn_out @ W_O (f32 store)
    gemm_tile<float, float, float, 0><<<dim3(DD / 64, NT / 64), blk, 0, stream>>>(
        buf0, W_O, out, DD, DD, DD, DD, DD);
}

// Round 3
// 910.306 us; speedup vs baseline: 2.8868x; 2.8868x over previous
//
#include <hip/hip_runtime.h>
#include <hip/hip_bf16.h>

// Problem constants
#define BB 2
#define SS 1024
#define DD 1024
#define NH 16
#define DH 64
#define MM 8
#define RR 128
#define NN 256
#define NT (BB*SS)          // 2048 tokens

using bf16 = __hip_bfloat16;

typedef __attribute__((ext_vector_type(8))) short short8;   // 8 bf16 (4 VGPRs) MFMA A/B frag
typedef __attribute__((ext_vector_type(4))) short short4v;  // 8-byte LDS load unit
typedef __attribute__((ext_vector_type(4))) float f32x4;    // MFMA C/D frag

__device__ __forceinline__ float ldf(const float* p, int i) { return p[i]; }
__device__ __forceinline__ float ldf(const bf16* p, int i) { return __bfloat162float(p[i]); }
__device__ __forceinline__ void stf(float* p, int i, float v) { p[i] = v; }
__device__ __forceinline__ void stf(bf16* p, int i, float v) { p[i] = __float2bfloat16(v); }

// Load 8 bf16 (as shorts) from LDS via two 8B reads (base only 8B-aligned).
__device__ __forceinline__ short8 lds_load8(const short* p) {
    short4v a = *(const short4v*)p;
    short4v b = *(const short4v*)(p + 4);
    short8 r;
    r[0] = a[0]; r[1] = a[1]; r[2] = a[2]; r[3] = a[3];
    r[4] = b[0]; r[5] = b[1]; r[6] = b[2]; r[7] = b[3];
    return r;
}

// Generic tiled GEMM: C[M,N] = A[M,K] @ B[K,N].
// BM=BN=64, BK=16, 256 threads, 4x4 per thread. M = gridDim.y*64.
// BMODE==0: B row-major [K,N] with ldb.
// BMODE==1: B is qk_f-style [8, K, 128]: B[k][n] = Bp[(n>>7)*K*128 + k*128 + (n&127)].
template <typename TA, typename TB, typename TC, int BMODE>
__global__ void gemm_tile(const TA* __restrict__ A, const TB* __restrict__ B,
                          TC* __restrict__ C, int Ndim, int Kdim,
                          int lda, int ldb, int ldc) {
    __shared__ float As[16][64];
    __shared__ float Bs[16][64];
    const int tid = threadIdx.x;
    const int bx = blockIdx.x;   // n tile
    const int by = blockIdx.y;   // m tile
    const int tx = tid & 15;     // 16 col-threads
    const int ty = tid >> 4;     // 16 row-threads
    const int m0 = by * 64 + ty * 4;
    const int n0 = bx * 64 + tx * 4;

    float acc[4][4];
#pragma unroll
    for (int i = 0; i < 4; ++i)
#pragma unroll
        for (int j = 0; j < 4; ++j) acc[i][j] = 0.f;

    for (int k0 = 0; k0 < Kdim; k0 += 16) {
#pragma unroll
        for (int i = 0; i < 4; ++i) {
            int e = tid + i * 256;
            int m = e >> 4, k = e & 15;
            As[k][m] = ldf(A, (by * 64 + m) * lda + k0 + k);
        }
#pragma unroll
        for (int i = 0; i < 4; ++i) {
            int e = tid + i * 256;
            int k = e >> 6, n = e & 63;
            int gn = bx * 64 + n;
            int gk = k0 + k;
            float v;
            if (BMODE == 0) v = ldf(B, gk * ldb + gn);
            else            v = ldf(B, (gn >> 7) * (Kdim * 128) + gk * 128 + (gn & 127));
            Bs[k][n] = v;
        }
        __syncthreads();
#pragma unroll
        for (int k = 0; k < 16; ++k) {
            float a[4], b[4];
#pragma unroll
            for (int i = 0; i < 4; ++i) a[i] = As[k][ty * 4 + i];
#pragma unroll
            for (int j = 0; j < 4; ++j) b[j] = Bs[k][tx * 4 + j];
#pragma unroll
            for (int i = 0; i < 4; ++i)
#pragma unroll
                for (int j = 0; j < 4; ++j) acc[i][j] += a[i] * b[j];
        }
        __syncthreads();
    }
#pragma unroll
    for (int i = 0; i < 4; ++i)
#pragma unroll
        for (int j = 0; j < 4; ++j)
            stf(C, (m0 + i) * ldc + n0 + j, acc[i][j]);
}

// Softmax over 256 logits, group-sum in chunks of 32, normalize -> g[t][8]
__global__ void gate_kernel(const float* __restrict__ logits, float* __restrict__ g) {
    const int t = blockIdx.x;
    const int n = threadIdx.x;   // 256
    __shared__ float red[256];
    __shared__ float probs[256];

    float v = logits[t * NN + n];
    red[n] = v;
    __syncthreads();
    for (int s = 128; s > 0; s >>= 1) {
        if (n < s) red[n] = fmaxf(red[n], red[n + s]);
        __syncthreads();
    }
    float mx = red[0];
    __syncthreads();
    float e = expf(v - mx);
    probs[n] = e;
    red[n] = e;
    __syncthreads();
    for (int s = 128; s > 0; s >>= 1) {
        if (n < s) red[n] += red[n + s];
        __syncthreads();
    }
    float denom = red[0];
    __syncthreads();
    if (n < 8) {
        float s = 0.f;
#pragma unroll
        for (int i = 0; i < 32; ++i) s += probs[n * 32 + i];
        red[n] = s / denom;
    }
    __syncthreads();
    if (n == 0) {
        float tot = 0.f;
#pragma unroll
        for (int m = 0; m < 8; ++m) tot += red[m];
        float inv = 1.0f / (tot + 1e-8f);
#pragma unroll
        for (int m = 0; m < 8; ++m) g[t * 8 + m] = red[m] * inv;
    }
}

// h[t][r] = sum_m allh[t][m*128+r] * g[t][m]
__global__ void combine_h(const float* __restrict__ allh, const float* __restrict__ g,
                          float* __restrict__ h) {
    int idx = blockIdx.x * blockDim.x + threadIdx.x;   // t*128+r
    int t = idx >> 7, r = idx & 127;
    float acc = 0.f;
#pragma unroll
    for (int m = 0; m < 8; ++m)
        acc += allh[t * 1024 + m * 128 + r] * g[t * 8 + m];
    h[idx] = acc;
}

// pre[t][m*128+r] = h[t][r] * g[t][m]
__global__ void make_pre(const float* __restrict__ h, const float* __restrict__ g,
                         float* __restrict__ pre) {
    int idx = blockIdx.x * blockDim.x + threadIdx.x;   // t*1024 + m*128 + r
    int t = idx >> 10;
    int mr = idx & 1023;
    int m = mr >> 7, r = mr & 127;
    pre[idx] = h[t * 128 + r] * g[t * 8 + m];
}

// -------------------- Flash attention (MFMA) --------------------
// One block per (b, h, 64-row Q-tile). 4 waves x 16 Q-rows. Causal K-tiles of 64.
// MFMA 16x16x32 bf16. Layouts (m89/m120 verified):
//   A-frag:  A[m=lane&15][k=quad*8+j]
//   B-frag:  B[k=quad*8+j][n=lane&15]  (loaded from row-major [n][k] storage)
//   C/D:     C[row=quad*4+reg][col=lane&15]
#define LDK 68   // padded halfword stride for K/V/P LDS tiles

__global__ __launch_bounds__(256) void flash_attn(const bf16* __restrict__ Q,
                                                  const bf16* __restrict__ K,
                                                  const bf16* __restrict__ V,
                                                  float* __restrict__ out) {
    const int qt = (int)gridDim.x - 1 - (int)blockIdx.x;  // heavy tiles dispatched first
    const int bh = blockIdx.y;
    const int b = bh >> 4;
    const int h = bh & 15;
    const int tid = threadIdx.x;
    const int wave = tid >> 6;
    const int lane = tid & 63;
    const int quad = lane >> 4;
    const int l15 = lane & 15;

    __shared__ short Ks[64 * LDK];        // Ks[kr][dh]  row-major
    __shared__ short Vt[64 * LDK];        // Vt[dh][kr]  (V transposed)
    __shared__ short Ps[4 * 16 * LDK];    // per-wave P[m][kr]

    // Q A-frags (held for the whole K-loop): rows q0 + wave*16 + l15
    const int q_row = qt * 64 + wave * 16 + l15;
    const bf16* qptr = Q + (size_t)(b * SS + q_row) * DD + h * DH + quad * 8;
    short8 aq0 = *(const short8*)qptr;         // k = 0..31
    short8 aq1 = *(const short8*)(qptr + 32);  // k = 32..63

    float m_r[4], l_r[4];
    f32x4 o[4];
#pragma unroll
    for (int r = 0; r < 4; ++r) { m_r[r] = -3.0e38f; l_r[r] = 0.f; }
#pragma unroll
    for (int c = 0; c < 4; ++c) o[c] = (f32x4)0.f;

    const float scale = 0.125f;  // 1/sqrt(64)

    for (int kt = 0; kt <= qt; ++kt) {
        const int kt0 = kt * 64;
        __syncthreads();
        // ---- stage K tile (row-major), coalesced global, 8B LDS writes ----
        {
            const int kr = tid >> 2;
            const int dhb = (tid & 3) * 16;
            const bf16* src = K + (size_t)(b * SS + kt0 + kr) * DD + h * DH + dhb;
            short4v v0 = *(const short4v*)(src);
            short4v v1 = *(const short4v*)(src + 4);
            short4v v2 = *(const short4v*)(src + 8);
            short4v v3 = *(const short4v*)(src + 12);
            short* dst = &Ks[kr * LDK + dhb];
            *(short4v*)(dst) = v0;
            *(short4v*)(dst + 4) = v1;
            *(short4v*)(dst + 8) = v2;
            *(short4v*)(dst + 12) = v3;
        }
        // ---- stage V tile transposed: packed-u32 conflict-free writes ----
        {
            const int krp = tid & 31;          // kr pair: 2*krp, 2*krp+1
            const int dhb = (tid >> 5) * 8;
            const bf16* s0 = V + (size_t)(b * SS + kt0 + 2 * krp) * DD + h * DH + dhb;
            short8 r0 = *(const short8*)s0;
            short8 r1 = *(const short8*)(s0 + DD);
#pragma unroll
            for (int i = 0; i < 8; ++i) {
                unsigned int pk = (unsigned short)r0[i] | ((unsigned int)(unsigned short)r1[i] << 16);
                *(unsigned int*)&Vt[(dhb + i) * LDK + 2 * krp] = pk;
            }
        }
        __syncthreads();

        // ---- S = Q K^T (4 col-chunks of 16) ----
        f32x4 s[4];
#pragma unroll
        for (int c = 0; c < 4; ++c) {
            short8 bk0 = lds_load8(&Ks[(c * 16 + l15) * LDK + quad * 8]);
            short8 bk1 = lds_load8(&Ks[(c * 16 + l15) * LDK + 32 + quad * 8]);
            f32x4 acc = (f32x4)0.f;
            acc = __builtin_amdgcn_mfma_f32_16x16x32_bf16(aq0, bk0, acc, 0, 0, 0);
            acc = __builtin_amdgcn_mfma_f32_16x16x32_bf16(aq1, bk1, acc, 0, 0, 0);
            s[c] = acc;
        }

        // scale + causal mask (diagonal tile only)
        const bool diag = (kt == qt);
#pragma unroll
        for (int c = 0; c < 4; ++c) {
#pragma unroll
            for (int r = 0; r < 4; ++r) {
                float v = s[c][r] * scale;
                if (diag) {
                    int row_rel = wave * 16 + quad * 4 + r;
                    int col_rel = c * 16 + l15;
                    if (col_rel > row_rel) v = -3.0e38f;
                }
                s[c][r] = v;
            }
        }

        // ---- online softmax in C-layout registers ----
        float p[4][4];
        float alpha[4];
#pragma unroll
        for (int r = 0; r < 4; ++r) {
            float mx = fmaxf(fmaxf(s[0][r], s[1][r]), fmaxf(s[2][r], s[3][r]));
            mx = fmaxf(mx, __shfl_xor(mx, 1));
            mx = fmaxf(mx, __shfl_xor(mx, 2));
            mx = fmaxf(mx, __shfl_xor(mx, 4));
            mx = fmaxf(mx, __shfl_xor(mx, 8));
            float new_m = fmaxf(m_r[r], mx);
            alpha[r] = __expf(m_r[r] - new_m);
            float rs = 0.f;
#pragma unroll
            for (int c = 0; c < 4; ++c) {
                float e = __expf(s[c][r] - new_m);
                p[c][r] = e;
                rs += e;
            }
            rs += __shfl_xor(rs, 1);
            rs += __shfl_xor(rs, 2);
            rs += __shfl_xor(rs, 4);
            rs += __shfl_xor(rs, 8);
            l_r[r] = l_r[r] * alpha[r] + rs;
            m_r[r] = new_m;
        }
#pragma unroll
        for (int c = 0; c < 4; ++c)
#pragma unroll
            for (int r = 0; r < 4; ++r) o[c][r] *= alpha[r];

        // ---- P: C-layout -> LDS -> A-layout ----
        short* pw = &Ps[wave * 16 * LDK];
#pragma unroll
        for (int c = 0; c < 4; ++c)
#pragma unroll
            for (int r = 0; r < 4; ++r) {
                bf16 hb = __float2bfloat16(p[c][r]);
                pw[(quad * 4 + r) * LDK + c * 16 + l15] = *(short*)&hb;
            }
        __syncthreads();  // also orders Ps write->read (wave-private, but cheap & safe)

        short8 ap0 = lds_load8(&pw[l15 * LDK + quad * 8]);        // kr 0..31
        short8 ap1 = lds_load8(&pw[l15 * LDK + 32 + quad * 8]);   // kr 32..63

        // ---- O += P V ----
#pragma unroll
        for (int c = 0; c < 4; ++c) {
            short8 bv0 = lds_load8(&Vt[(c * 16 + l15) * LDK + quad * 8]);
            short8 bv1 = lds_load8(&Vt[(c * 16 + l15) * LDK + 32 + quad * 8]);
            o[c] = __builtin_amdgcn_mfma_f32_16x16x32_bf16(ap0, bv0, o[c], 0, 0, 0);
            o[c] = __builtin_amdgcn_mfma_f32_16x16x32_bf16(ap1, bv1, o[c], 0, 0, 0);
        }
    }

    // ---- epilogue: O /= l, write f32 ----
#pragma unroll
    for (int c = 0; c < 4; ++c) {
#pragma unroll
        for (int r = 0; r < 4; ++r) {
            int row = qt * 64 + wave * 16 + quad * 4 + r;
            int col = c * 16 + l15;
            out[(size_t)(b * SS + row) * DD + h * DH + col] = o[c][r] / l_r[r];
        }
    }
}

extern "C" void kernel_launch(void* const* d_in, const int* in_sizes, int n_in,
                              void* d_out, int out_size, void* d_ws, size_t ws_size,
                              hipStream_t stream) {
    // Reference dtypes are float32 for ALL inputs and the output.
    const float* x    = (const float*)d_in[0];
    const float* qk_f = (const float*)d_in[1];
    const float* qk_r = (const float*)d_in[2];
    const float* v_f  = (const float*)d_in[3];
    const float* v_r  = (const float*)d_in[4];
    const float* Wg_q = (const float*)d_in[5];
    const float* Wg_k = (const float*)d_in[6];
    const float* Wg_v = (const float*)d_in[7];
    const float* W_O  = (const float*)d_in[8];
    float* out = (float*)d_out;

    float* ws = (float*)d_ws;
    float* buf0 = ws;                       // f32 [2048,1024] (logits -> all_h -> pre -> attn_out)
    float* gQ   = buf0 + NT * DD;
    float* gK   = gQ + NT * MM;
    float* gV   = gK + NT * MM;
    float* hQ   = gV + NT * MM;
    float* hK   = hQ + NT * RR;
    float* hV   = hK + NT * RR;
    bf16* Qb = (bf16*)(hV + NT * RR);       // bf16 [2048,1024] x3
    bf16* Kb = Qb + NT * DD;
    bf16* Vb = Kb + NT * DD;

    dim3 blk(256);

    // 1) Gates
    const float* Wgs[3] = {Wg_q, Wg_k, Wg_v};
    float* gs[3] = {gQ, gK, gV};
    for (int i = 0; i < 3; ++i) {
        gemm_tile<float, float, float, 0><<<dim3(NN / 64, NT / 64), blk, 0, stream>>>(
            x, Wgs[i], buf0, NN, DD, DD, NN, NN);
        gate_kernel<<<NT, 256, 0, stream>>>(buf0, gs[i]);
    }

    // 2) all_h (qk shared by Q and K), then h
    gemm_tile<float, float, float, 1><<<dim3(DD / 64, NT / 64), blk, 0, stream>>>(
        x, qk_f, buf0, MM * RR, DD, DD, 0, MM * RR);
    combine_h<<<NT * RR / 256, 256, 0, stream>>>(buf0, gQ, hQ);
    combine_h<<<NT * RR / 256, 256, 0, stream>>>(buf0, gK, hK);
    gemm_tile<float, float, float, 1><<<dim3(DD / 64, NT / 64), blk, 0, stream>>>(
        x, v_f, buf0, MM * RR, DD, DD, 0, MM * RR);
    combine_h<<<NT * RR / 256, 256, 0, stream>>>(buf0, gV, hV);

    // 3) restore -> Q, K, V (bf16); qk_r/v_r flatten to row-major [M*R, D]
    make_pre<<<NT * DD / 256, 256, 0, stream>>>(hQ, gQ, buf0);
    gemm_tile<float, float, bf16, 0><<<dim3(DD / 64, NT / 64), blk, 0, stream>>>(
        buf0, qk_r, Qb, DD, MM * RR, MM * RR, DD, DD);
    make_pre<<<NT * DD / 256, 256, 0, stream>>>(hK, gK, buf0);
    gemm_tile<float, float, bf16, 0><<<dim3(DD / 64, NT / 64), blk, 0, stream>>>(
        buf0, qk_r, Kb, DD, MM * RR, MM * RR, DD, DD);
    make_pre<<<NT * DD / 256, 256, 0, stream>>>(hV, gV, buf0);
    gemm_tile<float, float, bf16, 0><<<dim3(DD / 64, NT / 64), blk, 0, stream>>>(
        buf0, v_r, Vb, DD, MM * RR, MM * RR, DD, DD);

    // 4) flash attention (MFMA) -> buf0 (attn_out, [B,S,D] head-merged)
    flash_attn<<<dim3(SS / 64, BB * NH), blk, 0, stream>>>(Qb, Kb, Vb, buf0);

    // 5) out = attn_out @ W_O (f32 store)
    gemm_tile<float, float, float, 0><<<dim3(DD / 64, NT / 64), blk, 0, stream>>>(
        buf0, W_O, out, DD, DD, DD, DD, DD);
}

// Round 4
// 303.890 us; speedup vs baseline: 8.6473x; 2.9955x over previous
//
#include <hip/hip_runtime.h>
#include <hip/hip_bf16.h>

// Problem constants
#define BB 2
#define SS 1024
#define DD 1024
#define NH 16
#define DH 64
#define MM 8
#define RR 128
#define NN 256
#define NT (BB*SS)          // 2048 tokens

using bf16 = __hip_bfloat16;

typedef __attribute__((ext_vector_type(8))) short short8;   // 8 bf16 (4 VGPRs) MFMA A/B frag
typedef __attribute__((ext_vector_type(4))) short short4v;  // 8-byte unit
typedef __attribute__((ext_vector_type(4))) float f32x4;    // MFMA C/D frag

__device__ __forceinline__ void stf(float* p, size_t i, float v) { p[i] = v; }
__device__ __forceinline__ void stf(bf16* p, size_t i, float v) { p[i] = __float2bfloat16(v); }

// async 16B global->LDS (lane i lands at ldsbase + i*16; ldsbase wave-uniform)
#define GLD16(g, l) __builtin_amdgcn_global_load_lds( \
    (const __attribute__((address_space(1))) void*)(g), \
    (__attribute__((address_space(3))) void*)(l), 16, 0, 0)

// Load 8 bf16 (as shorts) from LDS via two 8B reads (base only 8B-aligned).
__device__ __forceinline__ short8 lds_load8(const short* p) {
    short4v a = *(const short4v*)p;
    short4v b = *(const short4v*)(p + 4);
    short8 r;
    r[0] = a[0]; r[1] = a[1]; r[2] = a[2]; r[3] = a[3];
    r[4] = b[0]; r[5] = b[1]; r[6] = b[2]; r[7] = b[3];
    return r;
}

// ---------------- MFMA GEMM ----------------
// C[M,N] = A[M,K] @ Bt[N,K]^T, A/Bt bf16 K-major, C f32 or bf16.
// Tile 128x128, BK=32, 256 threads = 4 waves (2x2), each wave 64x64 (4x4 frags).
// LDS chunk L (16B) holds row L>>2, global k-chunk (L&3) ^ ((row>>1)&3)  [XOR swizzle].
template <typename TC>
__global__ __launch_bounds__(256) void mfma_gemm(
    const bf16* __restrict__ Abase, const bf16* __restrict__ Btbase, TC* __restrict__ Cbase,
    int Kdim, int Ndim, long strideA, long strideB, long strideC, int4 bsel) {
    const int z = blockIdx.z;
    const int sel = (z == 0) ? bsel.x : (z == 1) ? bsel.y : (z == 2) ? bsel.z : bsel.w;
    const bf16* A  = Abase + (size_t)z * strideA;
    const bf16* Bt = Btbase + (size_t)sel * strideB;
    TC* C = Cbase + (size_t)z * strideC;

    const int tid = threadIdx.x;
    const int wave = tid >> 6, lane = tid & 63;
    const int quad = lane >> 4, l15 = lane & 15;
    const int wr = wave >> 1, wc = wave & 1;
    const int m0 = blockIdx.y * 128;
    const int n0 = blockIdx.x * 128;

    __shared__ bf16 As[128 * 32];
    __shared__ bf16 Bs[128 * 32];

    f32x4 acc[4][4];
#pragma unroll
    for (int i = 0; i < 4; ++i)
#pragma unroll
        for (int j = 0; j < 4; ++j) acc[i][j] = (f32x4)0.f;

    for (int k0 = 0; k0 < Kdim; k0 += 32) {
        __syncthreads();
#pragma unroll
        for (int i = 0; i < 2; ++i) {
            const int L = i * 256 + wave * 64 + lane;     // LDS chunk index (incl. lane)
            const int row = L >> 2;
            const int gch = (L & 3) ^ ((row >> 1) & 3);
            const int ldsbase = (i * 256 + wave * 64) * 8;  // wave-uniform, elements
            const bf16* ga = A + (size_t)(m0 + row) * Kdim + k0 + gch * 8;
            GLD16(ga, &As[ldsbase]);
            const bf16* gb = Bt + (size_t)(n0 + row) * Kdim + k0 + gch * 8;
            GLD16(gb, &Bs[ldsbase]);
        }
        __syncthreads();   // waits vmcnt(0): LDS tiles complete

        short8 aF[4], bF[4];
#pragma unroll
        for (int bi = 0; bi < 4; ++bi) {
            int m = wr * 64 + bi * 16 + l15;
            aF[bi] = *(const short8*)&As[(m * 4 + (quad ^ ((m >> 1) & 3))) * 8];
        }
#pragma unroll
        for (int bj = 0; bj < 4; ++bj) {
            int n = wc * 64 + bj * 16 + l15;
            bF[bj] = *(const short8*)&Bs[(n * 4 + (quad ^ ((n >> 1) & 3))) * 8];
        }
#pragma unroll
        for (int bi = 0; bi < 4; ++bi)
#pragma unroll
            for (int bj = 0; bj < 4; ++bj)
                acc[bi][bj] = __builtin_amdgcn_mfma_f32_16x16x32_bf16(aF[bi], bF[bj], acc[bi][bj], 0, 0, 0);
    }

#pragma unroll
    for (int bi = 0; bi < 4; ++bi)
#pragma unroll
        for (int bj = 0; bj < 4; ++bj)
#pragma unroll
            for (int r = 0; r < 4; ++r) {
                int row = m0 + wr * 64 + bi * 16 + quad * 4 + r;
                int col = n0 + wc * 64 + bj * 16 + l15;
                stf(C, (size_t)row * Ndim + col, acc[bi][bj][r]);
            }
}

// ---------------- fused convert/transpose (f32 -> bf16) ----------------
// Transpose jobs: dst[(g*R + r)*K + k] = src[(g*K + k)*R + r]   (K,R mult of 32)
// Copy job (G==0): dst[i] = bf16(src[i]), 4096 elems/tile.
struct ConvJobs {
    const float* src[9];
    bf16* dst[9];
    int K[9], R[9], G[9];
    int tEnd[9];   // cumulative tile counts
};

__global__ void convert_kernel(ConvJobs J) {
    __shared__ float tile[32][33];
    const int b = blockIdx.x;
    int j = 0;
    while (j < 8 && b >= J.tEnd[j]) ++j;
    const int local = b - (j > 0 ? J.tEnd[j - 1] : 0);
    const float* src = J.src[j];
    bf16* dst = J.dst[j];
    const int tid = threadIdx.x;

    if (J.G[j] == 0) {
        // elementwise cast: 4096 elems per tile, 16 per thread
        size_t base = (size_t)local * 4096 + (size_t)tid * 16;
        const float4* s4 = (const float4*)(src + base);
        short* d = (short*)(dst + base);
#pragma unroll
        for (int c = 0; c < 4; ++c) {
            float4 v = s4[c];
            short4v o;
            bf16 t0 = __float2bfloat16(v.x); o[0] = *(short*)&t0;
            bf16 t1 = __float2bfloat16(v.y); o[1] = *(short*)&t1;
            bf16 t2 = __float2bfloat16(v.z); o[2] = *(short*)&t2;
            bf16 t3 = __float2bfloat16(v.w); o[3] = *(short*)&t3;
            *(short4v*)(d + c * 4) = o;
        }
    } else {
        const int Kj = J.K[j], Rj = J.R[j];
        const int Rb = Rj >> 5, Kb = Kj >> 5;
        const int perG = Kb * Rb;
        const int g = local / perG;
        const int rem = local - g * perG;
        const int kb = rem / Rb, rb = rem - kb * Rb;
        const int tx = tid & 31, ty0 = tid >> 5;
        const float* s = src + ((size_t)(g * Kj + kb * 32) * Rj) + rb * 32 + tx;
#pragma unroll
        for (int p = 0; p < 4; ++p)
            tile[ty0 + p * 8][tx] = s[(size_t)(ty0 + p * 8) * Rj];
        __syncthreads();
        bf16* dd = dst + ((size_t)(g * Rj + rb * 32) * Kj) + kb * 32 + tx;
#pragma unroll
        for (int p = 0; p < 4; ++p)
            dd[(size_t)(ty0 + p * 8) * Kj] = __float2bfloat16(tile[tx][ty0 + p * 8]);
    }
}

// ---------------- gates ----------------
// Softmax over 256 bf16 logits, group-sum by 32, normalize -> g[t][8] f32.
__global__ void gate_kernel(const bf16* __restrict__ logitsAll, float* __restrict__ gAll) {
    const int t = blockIdx.x;
    const int z = blockIdx.y;
    const bf16* logits = logitsAll + (size_t)z * NT * NN;
    float* g = gAll + (size_t)z * NT * MM;
    const int n = threadIdx.x;   // 256
    __shared__ float red[256];
    __shared__ float probs[256];

    float v = __bfloat162float(logits[t * NN + n]);
    red[n] = v;
    __syncthreads();
    for (int s = 128; s > 0; s >>= 1) {
        if (n < s) red[n] = fmaxf(red[n], red[n + s]);
        __syncthreads();
    }
    float mx = red[0];
    __syncthreads();
    float e = expf(v - mx);
    probs[n] = e;
    red[n] = e;
    __syncthreads();
    for (int s = 128; s > 0; s >>= 1) {
        if (n < s) red[n] += red[n + s];
        __syncthreads();
    }
    float denom = red[0];
    __syncthreads();
    if (n < 8) {
        float s = 0.f;
#pragma unroll
        for (int i = 0; i < 32; ++i) s += probs[n * 32 + i];
        red[n] = s / denom;
    }
    __syncthreads();
    if (n == 0) {
        float tot = 0.f;
#pragma unroll
        for (int m = 0; m < 8; ++m) tot += red[m];
        float inv = 1.0f / (tot + 1e-8f);
#pragma unroll
        for (int m = 0; m < 8; ++m) g[t * 8 + m] = red[m] * inv;
    }
}

// ---------------- combine + make_pre fused ----------------
// h[t][r] = sum_m allh[t][m*128+r]*g[t][m]; pre[t][m*128+r] = h*g[t][m]  (bf16)
__global__ void combine_pre(const bf16* __restrict__ allh, const float* __restrict__ g,
                            bf16* __restrict__ pre) {
    int idx = blockIdx.x * 256 + threadIdx.x;   // t*128 + r
    int t = idx >> 7, r = idx & 127;
    float gv[8];
    float acc = 0.f;
#pragma unroll
    for (int m = 0; m < 8; ++m) {
        gv[m] = g[t * 8 + m];
        acc += __bfloat162float(allh[(size_t)t * 1024 + m * 128 + r]) * gv[m];
    }
#pragma unroll
    for (int m = 0; m < 8; ++m)
        pre[(size_t)t * 1024 + m * 128 + r] = __float2bfloat16(acc * gv[m]);
}

// -------------------- Flash attention (MFMA) --------------------
#define LDK 68   // padded halfword stride for K/V/P LDS tiles

__global__ __launch_bounds__(256) void flash_attn(const bf16* __restrict__ Q,
                                                  const bf16* __restrict__ K,
                                                  const bf16* __restrict__ V,
                                                  bf16* __restrict__ out) {
    const int qt = (int)gridDim.x - 1 - (int)blockIdx.x;  // heavy tiles first
    const int bh = blockIdx.y;
    const int b = bh >> 4;
    const int h = bh & 15;
    const int tid = threadIdx.x;
    const int wave = tid >> 6;
    const int lane = tid & 63;
    const int quad = lane >> 4;
    const int l15 = lane & 15;

    __shared__ short Ks[64 * LDK];        // Ks[kr][dh]
    __shared__ short Vt[64 * LDK];        // Vt[dh][kr]
    __shared__ short Ps[4 * 16 * LDK];    // per-wave P[m][kr]

    const int q_row = qt * 64 + wave * 16 + l15;
    const bf16* qptr = Q + (size_t)(b * SS + q_row) * DD + h * DH + quad * 8;
    short8 aq0 = *(const short8*)qptr;
    short8 aq1 = *(const short8*)(qptr + 32);

    float m_r[4], l_r[4];
    f32x4 o[4];
#pragma unroll
    for (int r = 0; r < 4; ++r) { m_r[r] = -3.0e38f; l_r[r] = 0.f; }
#pragma unroll
    for (int c = 0; c < 4; ++c) o[c] = (f32x4)0.f;

    const float scale = 0.125f;

    for (int kt = 0; kt <= qt; ++kt) {
        const int kt0 = kt * 64;
        __syncthreads();
        {
            const int kr = tid >> 2;
            const int dhb = (tid & 3) * 16;
            const bf16* src = K + (size_t)(b * SS + kt0 + kr) * DD + h * DH + dhb;
            short4v v0 = *(const short4v*)(src);
            short4v v1 = *(const short4v*)(src + 4);
            short4v v2 = *(const short4v*)(src + 8);
            short4v v3 = *(const short4v*)(src + 12);
            short* dst = &Ks[kr * LDK + dhb];
            *(short4v*)(dst) = v0;
            *(short4v*)(dst + 4) = v1;
            *(short4v*)(dst + 8) = v2;
            *(short4v*)(dst + 12) = v3;
        }
        {
            const int krp = tid & 31;
            const int dhb = (tid >> 5) * 8;
            const bf16* s0 = V + (size_t)(b * SS + kt0 + 2 * krp) * DD + h * DH + dhb;
            short8 r0 = *(const short8*)s0;
            short8 r1 = *(const short8*)(s0 + DD);
#pragma unroll
            for (int i = 0; i < 8; ++i) {
                unsigned int pk = (unsigned short)r0[i] | ((unsigned int)(unsigned short)r1[i] << 16);
                *(unsigned int*)&Vt[(dhb + i) * LDK + 2 * krp] = pk;
            }
        }
        __syncthreads();

        f32x4 s[4];
#pragma unroll
        for (int c = 0; c < 4; ++c) {
            short8 bk0 = lds_load8(&Ks[(c * 16 + l15) * LDK + quad * 8]);
            short8 bk1 = lds_load8(&Ks[(c * 16 + l15) * LDK + 32 + quad * 8]);
            f32x4 acc = (f32x4)0.f;
            acc = __builtin_amdgcn_mfma_f32_16x16x32_bf16(aq0, bk0, acc, 0, 0, 0);
            acc = __builtin_amdgcn_mfma_f32_16x16x32_bf16(aq1, bk1, acc, 0, 0, 0);
            s[c] = acc;
        }

        const bool diag = (kt == qt);
#pragma unroll
        for (int c = 0; c < 4; ++c) {
#pragma unroll
            for (int r = 0; r < 4; ++r) {
                float v = s[c][r] * scale;
                if (diag) {
                    int row_rel = wave * 16 + quad * 4 + r;
                    int col_rel = c * 16 + l15;
                    if (col_rel > row_rel) v = -3.0e38f;
                }
                s[c][r] = v;
            }
        }

        float p[4][4];
        float alpha[4];
#pragma unroll
        for (int r = 0; r < 4; ++r) {
            float mx = fmaxf(fmaxf(s[0][r], s[1][r]), fmaxf(s[2][r], s[3][r]));
            mx = fmaxf(mx, __shfl_xor(mx, 1));
            mx = fmaxf(mx, __shfl_xor(mx, 2));
            mx = fmaxf(mx, __shfl_xor(mx, 4));
            mx = fmaxf(mx, __shfl_xor(mx, 8));
            float new_m = fmaxf(m_r[r], mx);
            alpha[r] = __expf(m_r[r] - new_m);
            float rs = 0.f;
#pragma unroll
            for (int c = 0; c < 4; ++c) {
                float e = __expf(s[c][r] - new_m);
                p[c][r] = e;
                rs += e;
            }
            rs += __shfl_xor(rs, 1);
            rs += __shfl_xor(rs, 2);
            rs += __shfl_xor(rs, 4);
            rs += __shfl_xor(rs, 8);
            l_r[r] = l_r[r] * alpha[r] + rs;
            m_r[r] = new_m;
        }
#pragma unroll
        for (int c = 0; c < 4; ++c)
#pragma unroll
            for (int r = 0; r < 4; ++r) o[c][r] *= alpha[r];

        short* pw = &Ps[wave * 16 * LDK];
#pragma unroll
        for (int c = 0; c < 4; ++c)
#pragma unroll
            for (int r = 0; r < 4; ++r) {
                bf16 hb = __float2bfloat16(p[c][r]);
                pw[(quad * 4 + r) * LDK + c * 16 + l15] = *(short*)&hb;
            }
        __syncthreads();

        short8 ap0 = lds_load8(&pw[l15 * LDK + quad * 8]);
        short8 ap1 = lds_load8(&pw[l15 * LDK + 32 + quad * 8]);

#pragma unroll
        for (int c = 0; c < 4; ++c) {
            short8 bv0 = lds_load8(&Vt[(c * 16 + l15) * LDK + quad * 8]);
            short8 bv1 = lds_load8(&Vt[(c * 16 + l15) * LDK + 32 + quad * 8]);
            o[c] = __builtin_amdgcn_mfma_f32_16x16x32_bf16(ap0, bv0, o[c], 0, 0, 0);
            o[c] = __builtin_amdgcn_mfma_f32_16x16x32_bf16(ap1, bv1, o[c], 0, 0, 0);
        }
    }

#pragma unroll
    for (int c = 0; c < 4; ++c) {
#pragma unroll
        for (int r = 0; r < 4; ++r) {
            int row = qt * 64 + wave * 16 + quad * 4 + r;
            int col = c * 16 + l15;
            out[(size_t)(b * SS + row) * DD + h * DH + col] = __float2bfloat16(o[c][r] / l_r[r]);
        }
    }
}

extern "C" void kernel_launch(void* const* d_in, const int* in_sizes, int n_in,
                              void* d_out, int out_size, void* d_ws, size_t ws_size,
                              hipStream_t stream) {
    const float* x    = (const float*)d_in[0];
    const float* qk_f = (const float*)d_in[1];
    const float* qk_r = (const float*)d_in[2];
    const float* v_f  = (const float*)d_in[3];
    const float* v_r  = (const float*)d_in[4];
    const float* Wg_q = (const float*)d_in[5];
    const float* Wg_k = (const float*)d_in[6];
    const float* Wg_v = (const float*)d_in[7];
    const float* W_O  = (const float*)d_in[8];

    // Workspace layout, peak 23 MiB (proven safe: R2/R3 used 23.2 MiB).
    // Live-range aliasing documented per step; d_out doubles as allh scratch.
    char* w = (char*)d_ws;
    const size_t MB = 1 << 20;
    bf16* xb     = (bf16*)(w + 0);                 // 0..4 MiB      (dead after all_h)
    bf16* wg_bt  = (bf16*)(w + 4 * MB);            // 4..5.5        (dead after gate gemm)
    bf16* fbt    = (bf16*)(w + (size_t)(5.5 * MB));// 5.5..9.5      (dead after all_h)
    bf16* logits = (bf16*)(w + (size_t)(9.5 * MB));// 9.5..12.5     (dead after gate_kernel)
    float* gAll  = (float*)(w + (size_t)(12.5 * MB)); // 12.5..12.69 (dead after combineV)
    bf16* qkr_bt = (bf16*)(w + 13 * MB);           // 13..15        (dead after restoreK)
    bf16* vr_bt  = (bf16*)(w + 15 * MB);           // 15..17        (dead after restoreV)
    bf16* wo_bt  = (bf16*)(w + 17 * MB);           // 17..19        (live to end)
    bf16* pre    = (bf16*)(w + 19 * MB);           // 19..23        (reused x3; dead after restoreV)
    bf16* Qb     = (bf16*)(w + 0);                 // over xb       (after all_h)
    bf16* Kb     = (bf16*)(w + (size_t)(5.5 * MB));// over fbt
    bf16* Vb     = (bf16*)(w + (size_t)(9.5 * MB));// over logits+gAll+qkr_bt head
    bf16* attnb  = (bf16*)(w + 19 * MB);           // over pre      (after restoreV)
    bf16* allh   = (bf16*)d_out;                   // [2][2048][1024] bf16 = 8 MiB scratch
    float* out   = (float*)d_out;

    // 1) convert/transpose everything to bf16 (weights -> Bt[N][K])
    ConvJobs J;
    J.src[0] = qk_f; J.dst[0] = fbt;            J.K[0] = 1024; J.R[0] = 128;  J.G[0] = 8;
    J.src[1] = v_f;  J.dst[1] = fbt + 1024*1024;J.K[1] = 1024; J.R[1] = 128;  J.G[1] = 8;
    J.src[2] = qk_r; J.dst[2] = qkr_bt;         J.K[2] = 1024; J.R[2] = 1024; J.G[2] = 1;
    J.src[3] = v_r;  J.dst[3] = vr_bt;          J.K[3] = 1024; J.R[3] = 1024; J.G[3] = 1;
    J.src[4] = W_O;  J.dst[4] = wo_bt;          J.K[4] = 1024; J.R[4] = 1024; J.G[4] = 1;
    J.src[5] = Wg_q; J.dst[5] = wg_bt;              J.K[5] = 1024; J.R[5] = 256; J.G[5] = 1;
    J.src[6] = Wg_k; J.dst[6] = wg_bt + 256*1024;   J.K[6] = 1024; J.R[6] = 256; J.G[6] = 1;
    J.src[7] = Wg_v; J.dst[7] = wg_bt + 2*256*1024; J.K[7] = 1024; J.R[7] = 256; J.G[7] = 1;
    J.src[8] = x;    J.dst[8] = xb;             J.K[8] = 0;    J.R[8] = 0;    J.G[8] = 0;
    int tiles[9] = {1024, 1024, 1024, 1024, 1024, 256, 256, 256, 512};
    int cum = 0;
    for (int i = 0; i < 9; ++i) { cum += tiles[i]; J.tEnd[i] = cum; }
    convert_kernel<<<cum, 256, 0, stream>>>(J);

    // 2) gate logits (z=3): xb @ wg_bt -> logits (bf16)
    mfma_gemm<bf16><<<dim3(NN / 128, NT / 128, 3), 256, 0, stream>>>(
        xb, wg_bt, logits, DD, NN, 0, (long)NN * DD, (long)NT * NN, make_int4(0, 1, 2, 0));
    gate_kernel<<<dim3(NT, 3), 256, 0, stream>>>(logits, gAll);

    // 3) all_h (z=2: qk_f, v_f): xb @ fbt -> allh (bf16, in d_out)
    mfma_gemm<bf16><<<dim3(DD / 128, NT / 128, 2), 256, 0, stream>>>(
        xb, fbt, allh, DD, DD, 0, (long)DD * DD, (long)NT * DD, make_int4(0, 1, 0, 0));

    // 4) sequential combine+restore per Q/K/V (pre buffer reused)
    // Q
    combine_pre<<<NT * RR / 256, 256, 0, stream>>>(allh, gAll, pre);
    mfma_gemm<bf16><<<dim3(DD / 128, NT / 128, 1), 256, 0, stream>>>(
        pre, qkr_bt, Qb, DD, DD, 0, 0, 0, make_int4(0, 0, 0, 0));
    // K
    combine_pre<<<NT * RR / 256, 256, 0, stream>>>(allh, gAll + NT * MM, pre);
    mfma_gemm<bf16><<<dim3(DD / 128, NT / 128, 1), 256, 0, stream>>>(
        pre, qkr_bt, Kb, DD, DD, 0, 0, 0, make_int4(0, 0, 0, 0));
    // V
    combine_pre<<<NT * RR / 256, 256, 0, stream>>>(allh + (size_t)NT * DD, gAll + 2 * NT * MM, pre);
    mfma_gemm<bf16><<<dim3(DD / 128, NT / 128, 1), 256, 0, stream>>>(
        pre, vr_bt, Vb, DD, DD, 0, 0, 0, make_int4(0, 0, 0, 0));

    // 5) flash attention -> attnb (bf16)
    flash_attn<<<dim3(SS / 64, BB * NH), 256, 0, stream>>>(Qb, Kb, Vb, attnb);

    // 6) out = attnb @ W_O (f32, overwrites allh scratch in d_out)
    mfma_gemm<float><<<dim3(DD / 128, NT / 128, 1), 256, 0, stream>>>(
        attnb, wo_bt, out, DD, DD, 0, 0, 0, make_int4(0, 0, 0, 0));
}

// Round 5
// 238.360 us; speedup vs baseline: 11.0247x; 1.2749x over previous
//
#include <hip/hip_runtime.h>
#include <hip/hip_bf16.h>

// Problem constants
#define BB 2
#define SS 1024
#define DD 1024
#define NH 16
#define DH 64
#define MM 8
#define RR 128
#define NN 256
#define NT (BB*SS)          // 2048 tokens

using bf16 = __hip_bfloat16;

typedef __attribute__((ext_vector_type(8))) short short8;   // 8 bf16 (4 VGPRs) MFMA A/B frag
typedef __attribute__((ext_vector_type(4))) short short4v;  // 8-byte unit
typedef __attribute__((ext_vector_type(4))) float f32x4;    // MFMA C/D frag

__device__ __forceinline__ void stf(float* p, size_t i, float v) { p[i] = v; }
__device__ __forceinline__ void stf(bf16* p, size_t i, float v) { p[i] = __float2bfloat16(v); }

// async 16B global->LDS (lane i lands at ldsbase + i*16; ldsbase wave-uniform)
#define GLD16(g, l) __builtin_amdgcn_global_load_lds( \
    (const __attribute__((address_space(1))) void*)(g), \
    (__attribute__((address_space(3))) void*)(l), 16, 0, 0)

// Load 8 bf16 (as shorts) from LDS via two 8B reads (base only 8B-aligned).
__device__ __forceinline__ short8 lds_load8(const short* p) {
    short4v a = *(const short4v*)p;
    short4v b = *(const short4v*)(p + 4);
    short8 r;
    r[0] = a[0]; r[1] = a[1]; r[2] = a[2]; r[3] = a[3];
    r[4] = b[0]; r[5] = b[1]; r[6] = b[2]; r[7] = b[3];
    return r;
}

// ---------------- MFMA GEMM, z-batched with per-z operands ----------------
// C[M,N] = A[M,K] @ Bt[N,K]^T, bf16 K-major A/Bt. Tile 128x128, BK=32,
// 4 waves (2x2), 4x4 16x16x32 frags/wave. Per-z A/Bt/C/N; early-exit if
// this n-tile is beyond N[z] (lets one launch mix N=1024 and N=256 jobs).
struct GemmZ {
    const bf16* A[5];
    const bf16* Bt[5];
    void* C[5];
    int N[5];
};

template <typename TC>
__global__ __launch_bounds__(256) void mfma_gemm_z(GemmZ P, int Kdim) {
    const int z = blockIdx.z;
    const int Nz = P.N[z];
    const int n0 = blockIdx.x * 128;
    if (n0 >= Nz) return;
    const bf16* __restrict__ A  = P.A[z];
    const bf16* __restrict__ Bt = P.Bt[z];
    TC* __restrict__ C = (TC*)P.C[z];

    const int tid = threadIdx.x;
    const int wave = tid >> 6, lane = tid & 63;
    const int quad = lane >> 4, l15 = lane & 15;
    const int wr = wave >> 1, wc = wave & 1;
    const int m0 = blockIdx.y * 128;

    __shared__ bf16 As[128 * 32];
    __shared__ bf16 Bs[128 * 32];

    f32x4 acc[4][4];
#pragma unroll
    for (int i = 0; i < 4; ++i)
#pragma unroll
        for (int j = 0; j < 4; ++j) acc[i][j] = (f32x4)0.f;

    for (int k0 = 0; k0 < Kdim; k0 += 32) {
        __syncthreads();
#pragma unroll
        for (int i = 0; i < 2; ++i) {
            const int L = i * 256 + wave * 64 + lane;     // LDS 16B-chunk index
            const int row = L >> 2;
            const int gch = (L & 3) ^ ((row >> 1) & 3);   // XOR swizzle
            const int ldsbase = (i * 256 + wave * 64) * 8;
            const bf16* ga = A + (size_t)(m0 + row) * Kdim + k0 + gch * 8;
            GLD16(ga, &As[ldsbase]);
            const bf16* gb = Bt + (size_t)(n0 + row) * Kdim + k0 + gch * 8;
            GLD16(gb, &Bs[ldsbase]);
        }
        __syncthreads();   // vmcnt(0): tiles resident

        short8 aF[4], bF[4];
#pragma unroll
        for (int bi = 0; bi < 4; ++bi) {
            int m = wr * 64 + bi * 16 + l15;
            aF[bi] = *(const short8*)&As[(m * 4 + (quad ^ ((m >> 1) & 3))) * 8];
        }
#pragma unroll
        for (int bj = 0; bj < 4; ++bj) {
            int n = wc * 64 + bj * 16 + l15;
            bF[bj] = *(const short8*)&Bs[(n * 4 + (quad ^ ((n >> 1) & 3))) * 8];
        }
#pragma unroll
        for (int bi = 0; bi < 4; ++bi)
#pragma unroll
            for (int bj = 0; bj < 4; ++bj)
                acc[bi][bj] = __builtin_amdgcn_mfma_f32_16x16x32_bf16(aF[bi], bF[bj], acc[bi][bj], 0, 0, 0);
    }

#pragma unroll
    for (int bi = 0; bi < 4; ++bi)
#pragma unroll
        for (int bj = 0; bj < 4; ++bj)
#pragma unroll
            for (int r = 0; r < 4; ++r) {
                int row = m0 + wr * 64 + bi * 16 + quad * 4 + r;
                int col = n0 + wc * 64 + bj * 16 + l15;
                stf(C, (size_t)row * Nz + col, acc[bi][bj][r]);
            }
}

// ---------------- fused convert/transpose (f32 -> bf16) ----------------
// Transpose jobs: dst[(g*R + r)*K + k] = src[(g*K + k)*R + r]   (K,R mult of 32)
// Copy job (G==0): dst[i] = bf16(src[i]), 4096 elems/tile.
struct ConvJobs {
    const float* src[9];
    bf16* dst[9];
    int K[9], R[9], G[9];
    int tEnd[9];   // cumulative tile counts
};

__global__ void convert_kernel(ConvJobs J) {
    __shared__ float tile[32][33];
    const int b = blockIdx.x;
    int j = 0;
    while (j < 8 && b >= J.tEnd[j]) ++j;
    const int local = b - (j > 0 ? J.tEnd[j - 1] : 0);
    const float* src = J.src[j];
    bf16* dst = J.dst[j];
    const int tid = threadIdx.x;

    if (J.G[j] == 0) {
        size_t base = (size_t)local * 4096 + (size_t)tid * 16;
        const float4* s4 = (const float4*)(src + base);
        short* d = (short*)(dst + base);
#pragma unroll
        for (int c = 0; c < 4; ++c) {
            float4 v = s4[c];
            short4v o;
            bf16 t0 = __float2bfloat16(v.x); o[0] = *(short*)&t0;
            bf16 t1 = __float2bfloat16(v.y); o[1] = *(short*)&t1;
            bf16 t2 = __float2bfloat16(v.z); o[2] = *(short*)&t2;
            bf16 t3 = __float2bfloat16(v.w); o[3] = *(short*)&t3;
            *(short4v*)(d + c * 4) = o;
        }
    } else {
        const int Kj = J.K[j], Rj = J.R[j];
        const int Rb = Rj >> 5, Kb = Kj >> 5;
        const int perG = Kb * Rb;
        const int g = local / perG;
        const int rem = local - g * perG;
        const int kb = rem / Rb, rb = rem - kb * Rb;
        const int tx = tid & 31, ty0 = tid >> 5;
        const float* s = src + ((size_t)(g * Kj + kb * 32) * Rj) + rb * 32 + tx;
#pragma unroll
        for (int p = 0; p < 4; ++p)
            tile[ty0 + p * 8][tx] = s[(size_t)(ty0 + p * 8) * Rj];
        __syncthreads();
        bf16* dd = dst + ((size_t)(g * Rj + rb * 32) * Kj) + kb * 32 + tx;
#pragma unroll
        for (int p = 0; p < 4; ++p)
            dd[(size_t)(ty0 + p * 8) * Kj] = __float2bfloat16(tile[tx][ty0 + p * 8]);
    }
}

// ---------------- gates ----------------
__global__ void gate_kernel(const bf16* __restrict__ logitsAll, float* __restrict__ gAll) {
    const int t = blockIdx.x;
    const int z = blockIdx.y;
    const bf16* logits = logitsAll + (size_t)z * NT * NN;
    float* g = gAll + (size_t)z * NT * MM;
    const int n = threadIdx.x;   // 256
    __shared__ float red[256];
    __shared__ float probs[256];

    float v = __bfloat162float(logits[t * NN + n]);
    red[n] = v;
    __syncthreads();
    for (int s = 128; s > 0; s >>= 1) {
        if (n < s) red[n] = fmaxf(red[n], red[n + s]);
        __syncthreads();
    }
    float mx = red[0];
    __syncthreads();
    float e = expf(v - mx);
    probs[n] = e;
    red[n] = e;
    __syncthreads();
    for (int s = 128; s > 0; s >>= 1) {
        if (n < s) red[n] += red[n + s];
        __syncthreads();
    }
    float denom = red[0];
    __syncthreads();
    if (n < 8) {
        float s = 0.f;
#pragma unroll
        for (int i = 0; i < 32; ++i) s += probs[n * 32 + i];
        red[n] = s / denom;
    }
    __syncthreads();
    if (n == 0) {
        float tot = 0.f;
#pragma unroll
        for (int m = 0; m < 8; ++m) tot += red[m];
        float inv = 1.0f / (tot + 1e-8f);
#pragma unroll
        for (int m = 0; m < 8; ++m) g[t * 8 + m] = red[m] * inv;
    }
}

// ---------------- combine + make_pre, z-batched ----------------
// z=0: allh_qk -> preQ ; z=1: allh_qk -> preK ; z=2: allh_v -> preV IN-PLACE
// (each thread reads its 8 elems then writes the same 8 addresses).
__global__ void combine_pre3(const bf16* __restrict__ allh_base, const float* __restrict__ gAll,
                             bf16* __restrict__ preQ, bf16* __restrict__ preK,
                             bf16* __restrict__ preV) {
    const int z = blockIdx.y;
    int idx = blockIdx.x * 256 + threadIdx.x;   // t*128 + r
    int t = idx >> 7, r = idx & 127;
    const bf16* src = allh_base + (z == 2 ? (size_t)NT * DD : 0);
    bf16* dst = (z == 0) ? preQ : (z == 1) ? preK : preV;
    const float* g = gAll + (size_t)z * NT * MM + t * 8;
    float gv[8];
    float acc = 0.f;
#pragma unroll
    for (int m = 0; m < 8; ++m) {
        gv[m] = g[m];
        acc += __bfloat162float(src[(size_t)t * 1024 + m * 128 + r]) * gv[m];
    }
#pragma unroll
    for (int m = 0; m < 8; ++m)
        dst[(size_t)t * 1024 + m * 128 + r] = __float2bfloat16(acc * gv[m]);
}

// -------------------- Flash attention (MFMA) --------------------
#define LDK 68   // padded halfword stride for K/V/P LDS tiles

__global__ __launch_bounds__(256) void flash_attn(const bf16* __restrict__ Q,
                                                  const bf16* __restrict__ K,
                                                  const bf16* __restrict__ V,
                                                  bf16* __restrict__ out) {
    const int qt = (int)gridDim.x - 1 - (int)blockIdx.x;  // heavy tiles first
    const int bh = blockIdx.y;
    const int b = bh >> 4;
    const int h = bh & 15;
    const int tid = threadIdx.x;
    const int wave = tid >> 6;
    const int lane = tid & 63;
    const int quad = lane >> 4;
    const int l15 = lane & 15;

    __shared__ short Ks[64 * LDK];        // Ks[kr][dh]
    __shared__ short Vt[64 * LDK];        // Vt[dh][kr]
    __shared__ short Ps[4 * 16 * LDK];    // per-wave P[m][kr]

    const int q_row = qt * 64 + wave * 16 + l15;
    const bf16* qptr = Q + (size_t)(b * SS + q_row) * DD + h * DH + quad * 8;
    short8 aq0 = *(const short8*)qptr;
    short8 aq1 = *(const short8*)(qptr + 32);

    float m_r[4], l_r[4];
    f32x4 o[4];
#pragma unroll
    for (int r = 0; r < 4; ++r) { m_r[r] = -3.0e38f; l_r[r] = 0.f; }
#pragma unroll
    for (int c = 0; c < 4; ++c) o[c] = (f32x4)0.f;

    const float scale = 0.125f;

    for (int kt = 0; kt <= qt; ++kt) {
        const int kt0 = kt * 64;
        __syncthreads();
        {
            const int kr = tid >> 2;
            const int dhb = (tid & 3) * 16;
            const bf16* src = K + (size_t)(b * SS + kt0 + kr) * DD + h * DH + dhb;
            short4v v0 = *(const short4v*)(src);
            short4v v1 = *(const short4v*)(src + 4);
            short4v v2 = *(const short4v*)(src + 8);
            short4v v3 = *(const short4v*)(src + 12);
            short* dst = &Ks[kr * LDK + dhb];
            *(short4v*)(dst) = v0;
            *(short4v*)(dst + 4) = v1;
            *(short4v*)(dst + 8) = v2;
            *(short4v*)(dst + 12) = v3;
        }
        {
            const int krp = tid & 31;
            const int dhb = (tid >> 5) * 8;
            const bf16* s0 = V + (size_t)(b * SS + kt0 + 2 * krp) * DD + h * DH + dhb;
            short8 r0 = *(const short8*)s0;
            short8 r1 = *(const short8*)(s0 + DD);
#pragma unroll
            for (int i = 0; i < 8; ++i) {
                unsigned int pk = (unsigned short)r0[i] | ((unsigned int)(unsigned short)r1[i] << 16);
                *(unsigned int*)&Vt[(dhb + i) * LDK + 2 * krp] = pk;
            }
        }
        __syncthreads();

        f32x4 s[4];
#pragma unroll
        for (int c = 0; c < 4; ++c) {
            short8 bk0 = lds_load8(&Ks[(c * 16 + l15) * LDK + quad * 8]);
            short8 bk1 = lds_load8(&Ks[(c * 16 + l15) * LDK + 32 + quad * 8]);
            f32x4 acc = (f32x4)0.f;
            acc = __builtin_amdgcn_mfma_f32_16x16x32_bf16(aq0, bk0, acc, 0, 0, 0);
            acc = __builtin_amdgcn_mfma_f32_16x16x32_bf16(aq1, bk1, acc, 0, 0, 0);
            s[c] = acc;
        }

        const bool diag = (kt == qt);
#pragma unroll
        for (int c = 0; c < 4; ++c) {
#pragma unroll
            for (int r = 0; r < 4; ++r) {
                float v = s[c][r] * scale;
                if (diag) {
                    int row_rel = wave * 16 + quad * 4 + r;
                    int col_rel = c * 16 + l15;
                    if (col_rel > row_rel) v = -3.0e38f;
                }
                s[c][r] = v;
            }
        }

        float p[4][4];
        float alpha[4];
#pragma unroll
        for (int r = 0; r < 4; ++r) {
            float mx = fmaxf(fmaxf(s[0][r], s[1][r]), fmaxf(s[2][r], s[3][r]));
            mx = fmaxf(mx, __shfl_xor(mx, 1));
            mx = fmaxf(mx, __shfl_xor(mx, 2));
            mx = fmaxf(mx, __shfl_xor(mx, 4));
            mx = fmaxf(mx, __shfl_xor(mx, 8));
            float new_m = fmaxf(m_r[r], mx);
            alpha[r] = __expf(m_r[r] - new_m);
            float rs = 0.f;
#pragma unroll
            for (int c = 0; c < 4; ++c) {
                float e = __expf(s[c][r] - new_m);
                p[c][r] = e;
                rs += e;
            }
            rs += __shfl_xor(rs, 1);
            rs += __shfl_xor(rs, 2);
            rs += __shfl_xor(rs, 4);
            rs += __shfl_xor(rs, 8);
            l_r[r] = l_r[r] * alpha[r] + rs;
            m_r[r] = new_m;
        }
#pragma unroll
        for (int c = 0; c < 4; ++c)
#pragma unroll
            for (int r = 0; r < 4; ++r) o[c][r] *= alpha[r];

        // P: C-layout -> wave-private LDS slab -> A-layout. No barrier needed:
        // Ps is wave-private; same-wave DS ops are ordered and the compiler
        // inserts lgkmcnt waits for the dependent reads.
        short* pw = &Ps[wave * 16 * LDK];
#pragma unroll
        for (int c = 0; c < 4; ++c)
#pragma unroll
            for (int r = 0; r < 4; ++r) {
                bf16 hb = __float2bfloat16(p[c][r]);
                pw[(quad * 4 + r) * LDK + c * 16 + l15] = *(short*)&hb;
            }

        short8 ap0 = lds_load8(&pw[l15 * LDK + quad * 8]);
        short8 ap1 = lds_load8(&pw[l15 * LDK + 32 + quad * 8]);

#pragma unroll
        for (int c = 0; c < 4; ++c) {
            short8 bv0 = lds_load8(&Vt[(c * 16 + l15) * LDK + quad * 8]);
            short8 bv1 = lds_load8(&Vt[(c * 16 + l15) * LDK + 32 + quad * 8]);
            o[c] = __builtin_amdgcn_mfma_f32_16x16x32_bf16(ap0, bv0, o[c], 0, 0, 0);
            o[c] = __builtin_amdgcn_mfma_f32_16x16x32_bf16(ap1, bv1, o[c], 0, 0, 0);
        }
    }

#pragma unroll
    for (int c = 0; c < 4; ++c) {
#pragma unroll
        for (int r = 0; r < 4; ++r) {
            int row = qt * 64 + wave * 16 + quad * 4 + r;
            int col = c * 16 + l15;
            out[(size_t)(b * SS + row) * DD + h * DH + col] = __float2bfloat16(o[c][r] / l_r[r]);
        }
    }
}

extern "C" void kernel_launch(void* const* d_in, const int* in_sizes, int n_in,
                              void* d_out, int out_size, void* d_ws, size_t ws_size,
                              hipStream_t stream) {
    const float* x    = (const float*)d_in[0];
    const float* qk_f = (const float*)d_in[1];
    const float* qk_r = (const float*)d_in[2];
    const float* v_f  = (const float*)d_in[3];
    const float* v_r  = (const float*)d_in[4];
    const float* Wg_q = (const float*)d_in[5];
    const float* Wg_k = (const float*)d_in[6];
    const float* Wg_v = (const float*)d_in[7];
    const float* W_O  = (const float*)d_in[8];

    // Workspace epochs (peak 22 MiB <= proven 23.19 MiB). d_out (8 MiB) doubles
    // as scratch: allh [B..D], preV in-place over allh_v [D..E], Qb [E..flash].
    // ws:  0..4    xb        -> preQ (D)      -> attnb (F)
    //      4..5.5  wg_bt     -> preK head (D)
    //      5.5..9.5 fbt      -> preK tail / Kb head
    //      8..12            -> Kb (E)   (over dead fbt tail + logits head)
    //      9.5..12.5 logits  (dead after gate_kernel)
    //      12..16           -> Vb (E)   (over dead logits tail + gAll + free)
    //      12.5..12.7 gAll   (dead after combine_pre3)
    //      16..18  qkr_bt   | 18..20 vr_bt | 20..22 wo_bt  (epoch A, stable)
    char* w = (char*)d_ws;
    const size_t MB = 1 << 20;
    bf16* xb     = (bf16*)(w + 0);
    bf16* wg_bt  = (bf16*)(w + 4 * MB);
    bf16* fbt    = (bf16*)(w + (size_t)(5.5 * MB));
    bf16* logits = (bf16*)(w + (size_t)(9.5 * MB));
    float* gAll  = (float*)(w + (size_t)(12.5 * MB));
    bf16* qkr_bt = (bf16*)(w + 16 * MB);
    bf16* vr_bt  = (bf16*)(w + 18 * MB);
    bf16* wo_bt  = (bf16*)(w + 20 * MB);
    bf16* preQ   = (bf16*)(w + 0);
    bf16* preK   = (bf16*)(w + 4 * MB);
    bf16* Kb     = (bf16*)(w + 8 * MB);
    bf16* Vb     = (bf16*)(w + 12 * MB);
    bf16* attnb  = (bf16*)(w + 0);
    bf16* allh   = (bf16*)d_out;              // [2][2048][1024] bf16 = 8 MiB
    bf16* preV   = allh + (size_t)NT * DD;    // in-place over allh_v
    bf16* Qb     = (bf16*)d_out;              // over dead allh_qk
    float* out   = (float*)d_out;

    // 1) convert/transpose all inputs to bf16 (weights -> Bt[N][K])
    ConvJobs J;
    J.src[0] = qk_f; J.dst[0] = fbt;              J.K[0] = 1024; J.R[0] = 128;  J.G[0] = 8;
    J.src[1] = v_f;  J.dst[1] = fbt + 1024*1024;  J.K[1] = 1024; J.R[1] = 128;  J.G[1] = 8;
    J.src[2] = qk_r; J.dst[2] = qkr_bt;           J.K[2] = 1024; J.R[2] = 1024; J.G[2] = 1;
    J.src[3] = v_r;  J.dst[3] = vr_bt;            J.K[3] = 1024; J.R[3] = 1024; J.G[3] = 1;
    J.src[4] = W_O;  J.dst[4] = wo_bt;            J.K[4] = 1024; J.R[4] = 1024; J.G[4] = 1;
    J.src[5] = Wg_q; J.dst[5] = wg_bt;            J.K[5] = 1024; J.R[5] = 256;  J.G[5] = 1;
    J.src[6] = Wg_k; J.dst[6] = wg_bt + 256*1024; J.K[6] = 1024; J.R[6] = 256;  J.G[6] = 1;
    J.src[7] = Wg_v; J.dst[7] = wg_bt + 2*256*1024; J.K[7] = 1024; J.R[7] = 256; J.G[7] = 1;
    J.src[8] = x;    J.dst[8] = xb;               J.K[8] = 0;    J.R[8] = 0;    J.G[8] = 0;
    int tiles[9] = {1024, 1024, 1024, 1024, 1024, 256, 256, 256, 512};
    int cum = 0;
    for (int i = 0; i < 9; ++i) { cum += tiles[i]; J.tEnd[i] = cum; }
    convert_kernel<<<cum, 256, 0, stream>>>(J);

    // 2) all projections in ONE launch (z=5): all_h(qk), all_h(v), 3 gate logits
    GemmZ Pp;
    Pp.A[0] = Pp.A[1] = Pp.A[2] = Pp.A[3] = Pp.A[4] = xb;
    Pp.Bt[0] = fbt;             Pp.Bt[1] = fbt + 1024*1024;
    Pp.Bt[2] = wg_bt;           Pp.Bt[3] = wg_bt + 256*1024;  Pp.Bt[4] = wg_bt + 2*256*1024;
    Pp.C[0] = allh;             Pp.C[1] = allh + (size_t)NT * DD;
    Pp.C[2] = logits;           Pp.C[3] = logits + (size_t)NT * NN;
    Pp.C[4] = logits + 2 * (size_t)NT * NN;
    Pp.N[0] = 1024; Pp.N[1] = 1024; Pp.N[2] = 256; Pp.N[3] = 256; Pp.N[4] = 256;
    mfma_gemm_z<bf16><<<dim3(8, 16, 5), 256, 0, stream>>>(Pp, DD);

    // 3) gate softmax+group -> gAll
    gate_kernel<<<dim3(NT, 3), 256, 0, stream>>>(logits, gAll);

    // 4) combine+make_pre, all three in one launch (preV in-place in d_out)
    combine_pre3<<<dim3(NT * RR / 256, 3), 256, 0, stream>>>(allh, gAll, preQ, preK, preV);

    // 5) restore Q,K,V in ONE launch (z=3, 384 blocks)
    GemmZ Pr;
    Pr.A[0] = preQ; Pr.A[1] = preK; Pr.A[2] = preV;
    Pr.Bt[0] = qkr_bt; Pr.Bt[1] = qkr_bt; Pr.Bt[2] = vr_bt;
    Pr.C[0] = Qb; Pr.C[1] = Kb; Pr.C[2] = Vb;
    Pr.N[0] = Pr.N[1] = Pr.N[2] = 1024;
    Pr.A[3] = Pr.A[4] = nullptr; Pr.Bt[3] = Pr.Bt[4] = nullptr;
    Pr.C[3] = Pr.C[4] = nullptr; Pr.N[3] = Pr.N[4] = 0;
    mfma_gemm_z<bf16><<<dim3(8, 16, 3), 256, 0, stream>>>(Pr, DD);

    // 6) flash attention -> attnb
    flash_attn<<<dim3(SS / 64, BB * NH), 256, 0, stream>>>(Qb, Kb, Vb, attnb);

    // 7) out = attnb @ W_O (f32 into d_out; Qb dead after flash)
    GemmZ Po;
    Po.A[0] = attnb; Po.Bt[0] = wo_bt; Po.C[0] = out; Po.N[0] = 1024;
    for (int i = 1; i < 5; ++i) { Po.A[i] = nullptr; Po.Bt[i] = nullptr; Po.C[i] = nullptr; Po.N[i] = 0; }
    mfma_gemm_z<float><<<dim3(8, 16, 1), 256, 0, stream>>>(Po, DD);
}

// Round 6
// 224.986 us; speedup vs baseline: 11.6800x; 1.0594x over previous
//
#include <hip/hip_runtime.h>
#include <hip/hip_bf16.h>

// Problem constants
#define BB 2
#define SS 1024
#define DD 1024
#define NH 16
#define DH 64
#define MM 8
#define RR 128
#define NN 256
#define NT (BB*SS)          // 2048 tokens

using bf16 = __hip_bfloat16;

typedef __attribute__((ext_vector_type(8))) short short8;   // 8 bf16 (4 VGPRs) MFMA A/B frag
typedef __attribute__((ext_vector_type(4))) short short4v;  // 8-byte unit
typedef __attribute__((ext_vector_type(4))) float f32x4;    // MFMA C/D frag

__device__ __forceinline__ void stf(float* p, size_t i, float v) { p[i] = v; }
__device__ __forceinline__ void stf(bf16* p, size_t i, float v) { p[i] = __float2bfloat16(v); }

// async 16B global->LDS (lane i lands at ldsbase + i*16; ldsbase wave-uniform)
#define GLD16(g, l) __builtin_amdgcn_global_load_lds( \
    (const __attribute__((address_space(1))) void*)(g), \
    (__attribute__((address_space(3))) void*)(l), 16, 0, 0)

// Load 8 bf16 (as shorts) from LDS via two 8B reads (base only 8B-aligned).
__device__ __forceinline__ short8 lds_load8(const short* p) {
    short4v a = *(const short4v*)p;
    short4v b = *(const short4v*)(p + 4);
    short8 r;
    r[0] = a[0]; r[1] = a[1]; r[2] = a[2]; r[3] = a[3];
    r[4] = b[0]; r[5] = b[1]; r[6] = b[2]; r[7] = b[3];
    return r;
}

// ---------------- MFMA GEMM, z-batched with per-z operands ----------------
// C[M,N] = A[M,K] @ Bt[N,K]^T, bf16 K-major A/Bt. Tile 128x128, BK=32,
// 4 waves (2x2), 4x4 16x16x32 frags/wave. Per-z A/Bt/C/N; early-exit if
// this n-tile is beyond N[z].
struct GemmZ {
    const bf16* A[5];
    const bf16* Bt[5];
    void* C[5];
    int N[5];
};

template <typename TC>
__global__ __launch_bounds__(256) void mfma_gemm_z(GemmZ P, int Kdim) {
    const int z = blockIdx.z;
    const int Nz = P.N[z];
    const int n0 = blockIdx.x * 128;
    if (n0 >= Nz) return;
    const bf16* __restrict__ A  = P.A[z];
    const bf16* __restrict__ Bt = P.Bt[z];
    TC* __restrict__ C = (TC*)P.C[z];

    const int tid = threadIdx.x;
    const int wave = tid >> 6, lane = tid & 63;
    const int quad = lane >> 4, l15 = lane & 15;
    const int wr = wave >> 1, wc = wave & 1;
    const int m0 = blockIdx.y * 128;

    __shared__ bf16 As[128 * 32];
    __shared__ bf16 Bs[128 * 32];

    f32x4 acc[4][4];
#pragma unroll
    for (int i = 0; i < 4; ++i)
#pragma unroll
        for (int j = 0; j < 4; ++j) acc[i][j] = (f32x4)0.f;

    for (int k0 = 0; k0 < Kdim; k0 += 32) {
        __syncthreads();
#pragma unroll
        for (int i = 0; i < 2; ++i) {
            const int L = i * 256 + wave * 64 + lane;     // LDS 16B-chunk index
            const int row = L >> 2;
            const int gch = (L & 3) ^ ((row >> 1) & 3);   // XOR swizzle
            const int ldsbase = (i * 256 + wave * 64) * 8;
            const bf16* ga = A + (size_t)(m0 + row) * Kdim + k0 + gch * 8;
            GLD16(ga, &As[ldsbase]);
            const bf16* gb = Bt + (size_t)(n0 + row) * Kdim + k0 + gch * 8;
            GLD16(gb, &Bs[ldsbase]);
        }
        __syncthreads();   // vmcnt(0): tiles resident

        short8 aF[4], bF[4];
#pragma unroll
        for (int bi = 0; bi < 4; ++bi) {
            int m = wr * 64 + bi * 16 + l15;
            aF[bi] = *(const short8*)&As[(m * 4 + (quad ^ ((m >> 1) & 3))) * 8];
        }
#pragma unroll
        for (int bj = 0; bj < 4; ++bj) {
            int n = wc * 64 + bj * 16 + l15;
            bF[bj] = *(const short8*)&Bs[(n * 4 + (quad ^ ((n >> 1) & 3))) * 8];
        }
#pragma unroll
        for (int bi = 0; bi < 4; ++bi)
#pragma unroll
            for (int bj = 0; bj < 4; ++bj)
                acc[bi][bj] = __builtin_amdgcn_mfma_f32_16x16x32_bf16(aF[bi], bF[bj], acc[bi][bj], 0, 0, 0);
    }

#pragma unroll
    for (int bi = 0; bi < 4; ++bi)
#pragma unroll
        for (int bj = 0; bj < 4; ++bj)
#pragma unroll
            for (int r = 0; r < 4; ++r) {
                int row = m0 + wr * 64 + bi * 16 + quad * 4 + r;
                int col = n0 + wc * 64 + bj * 16 + l15;
                stf(C, (size_t)row * Nz + col, acc[bi][bj][r]);
            }
}

// ---------------- MFMA GEMM, 64x128 tile (better fill for small grids) ----
// Same layout conventions; 4 waves 2x2, wave = 32x64 (2x4 frags).
template <typename TC>
__global__ __launch_bounds__(256) void mfma_gemm_64(
    const bf16* __restrict__ A, const bf16* __restrict__ Bt, TC* __restrict__ C,
    int Kdim, int Ndim) {
    const int tid = threadIdx.x;
    const int wave = tid >> 6, lane = tid & 63;
    const int quad = lane >> 4, l15 = lane & 15;
    const int wr = wave >> 1, wc = wave & 1;
    const int m0 = blockIdx.y * 64;
    const int n0 = blockIdx.x * 128;

    __shared__ bf16 As[64 * 32];
    __shared__ bf16 Bs[128 * 32];

    f32x4 acc[2][4];
#pragma unroll
    for (int i = 0; i < 2; ++i)
#pragma unroll
        for (int j = 0; j < 4; ++j) acc[i][j] = (f32x4)0.f;

    for (int k0 = 0; k0 < Kdim; k0 += 32) {
        __syncthreads();
        {   // A: 256 chunks, one per thread
            const int L = wave * 64 + lane;
            const int row = L >> 2;
            const int gch = (L & 3) ^ ((row >> 1) & 3);
            GLD16(A + (size_t)(m0 + row) * Kdim + k0 + gch * 8, &As[(wave * 64) * 8]);
        }
#pragma unroll
        for (int i = 0; i < 2; ++i) {   // B: 512 chunks
            const int L = i * 256 + wave * 64 + lane;
            const int row = L >> 2;
            const int gch = (L & 3) ^ ((row >> 1) & 3);
            GLD16(Bt + (size_t)(n0 + row) * Kdim + k0 + gch * 8, &Bs[(i * 256 + wave * 64) * 8]);
        }
        __syncthreads();

        short8 aF[2], bF[4];
#pragma unroll
        for (int bi = 0; bi < 2; ++bi) {
            int m = wr * 32 + bi * 16 + l15;
            aF[bi] = *(const short8*)&As[(m * 4 + (quad ^ ((m >> 1) & 3))) * 8];
        }
#pragma unroll
        for (int bj = 0; bj < 4; ++bj) {
            int n = wc * 64 + bj * 16 + l15;
            bF[bj] = *(const short8*)&Bs[(n * 4 + (quad ^ ((n >> 1) & 3))) * 8];
        }
#pragma unroll
        for (int bi = 0; bi < 2; ++bi)
#pragma unroll
            for (int bj = 0; bj < 4; ++bj)
                acc[bi][bj] = __builtin_amdgcn_mfma_f32_16x16x32_bf16(aF[bi], bF[bj], acc[bi][bj], 0, 0, 0);
    }

#pragma unroll
    for (int bi = 0; bi < 2; ++bi)
#pragma unroll
        for (int bj = 0; bj < 4; ++bj)
#pragma unroll
            for (int r = 0; r < 4; ++r) {
                int row = m0 + wr * 32 + bi * 16 + quad * 4 + r;
                int col = n0 + wc * 64 + bj * 16 + l15;
                stf(C, (size_t)row * Ndim + col, acc[bi][bj][r]);
            }
}

// ---------------- fused convert/transpose (f32 -> bf16) ----------------
struct ConvJobs {
    const float* src[9];
    bf16* dst[9];
    int K[9], R[9], G[9];
    int tEnd[9];   // cumulative tile counts
};

__global__ void convert_kernel(ConvJobs J) {
    __shared__ float tile[32][33];
    const int b = blockIdx.x;
    int j = 0;
    while (j < 8 && b >= J.tEnd[j]) ++j;
    const int local = b - (j > 0 ? J.tEnd[j - 1] : 0);
    const float* src = J.src[j];
    bf16* dst = J.dst[j];
    const int tid = threadIdx.x;

    if (J.G[j] == 0) {
        size_t base = (size_t)local * 4096 + (size_t)tid * 16;
        const float4* s4 = (const float4*)(src + base);
        short* d = (short*)(dst + base);
#pragma unroll
        for (int c = 0; c < 4; ++c) {
            float4 v = s4[c];
            short4v o;
            bf16 t0 = __float2bfloat16(v.x); o[0] = *(short*)&t0;
            bf16 t1 = __float2bfloat16(v.y); o[1] = *(short*)&t1;
            bf16 t2 = __float2bfloat16(v.z); o[2] = *(short*)&t2;
            bf16 t3 = __float2bfloat16(v.w); o[3] = *(short*)&t3;
            *(short4v*)(d + c * 4) = o;
        }
    } else {
        const int Kj = J.K[j], Rj = J.R[j];
        const int Rb = Rj >> 5, Kb = Kj >> 5;
        const int perG = Kb * Rb;
        const int g = local / perG;
        const int rem = local - g * perG;
        const int kb = rem / Rb, rb = rem - kb * Rb;
        const int tx = tid & 31, ty0 = tid >> 5;
        const float* s = src + ((size_t)(g * Kj + kb * 32) * Rj) + rb * 32 + tx;
#pragma unroll
        for (int p = 0; p < 4; ++p)
            tile[ty0 + p * 8][tx] = s[(size_t)(ty0 + p * 8) * Rj];
        __syncthreads();
        bf16* dd = dst + ((size_t)(g * Rj + rb * 32) * Kj) + kb * 32 + tx;
#pragma unroll
        for (int p = 0; p < 4; ++p)
            dd[(size_t)(ty0 + p * 8) * Kj] = __float2bfloat16(tile[tx][ty0 + p * 8]);
    }
}

// ---------------- fused gates + combine + make_pre ----------------
// One block per token. Computes 3 softmax-grouped gates (f32, identical math
// to the R5 two-kernel path), then preQ/preK/preV rows. preV is IN-PLACE over
// allh_v: barrier between all reads and the writes; address sets per r0 are
// touched only by the two threads with that r0 (halves write disjoint m).
__global__ void gate_combine(const bf16* __restrict__ logitsAll,
                             const bf16* __restrict__ allh,
                             bf16* __restrict__ preQ, bf16* __restrict__ preK,
                             bf16* __restrict__ preV) {
    const int t = blockIdx.x;
    const int n = threadIdx.x;   // 256
    __shared__ float red[256];
    __shared__ float probs[256];
    __shared__ float gsh[3][8];

#pragma unroll
    for (int z = 0; z < 3; ++z) {
        float v = __bfloat162float(logitsAll[(size_t)z * NT * NN + (size_t)t * NN + n]);
        red[n] = v;
        __syncthreads();
        for (int s = 128; s > 0; s >>= 1) {
            if (n < s) red[n] = fmaxf(red[n], red[n + s]);
            __syncthreads();
        }
        float mx = red[0];
        __syncthreads();
        float e = expf(v - mx);
        probs[n] = e;
        red[n] = e;
        __syncthreads();
        for (int s = 128; s > 0; s >>= 1) {
            if (n < s) red[n] += red[n + s];
            __syncthreads();
        }
        float denom = red[0];
        __syncthreads();
        if (n < 8) {
            float s = 0.f;
#pragma unroll
            for (int i = 0; i < 32; ++i) s += probs[n * 32 + i];
            red[n] = s / denom;
        }
        __syncthreads();
        if (n == 0) {
            float tot = 0.f;
#pragma unroll
            for (int m = 0; m < 8; ++m) tot += red[m];
            float inv = 1.0f / (tot + 1e-8f);
#pragma unroll
            for (int m = 0; m < 8; ++m) gsh[z][m] = red[m] * inv;
        }
        __syncthreads();
    }

    const int r0 = n & 127;
    const int half = n >> 7;
    const bf16* src_qk = allh + (size_t)t * 1024;
    const bf16* src_v  = allh + (size_t)NT * DD + (size_t)t * 1024;
    float hq = 0.f, hk = 0.f, hv = 0.f;
#pragma unroll
    for (int m = 0; m < 8; ++m) {
        float aqk = __bfloat162float(src_qk[m * 128 + r0]);
        float av  = __bfloat162float(src_v[m * 128 + r0]);
        hq += aqk * gsh[0][m];
        hk += aqk * gsh[1][m];
        hv += av  * gsh[2][m];
    }
    __syncthreads();   // all allh_v reads complete before in-place preV writes
#pragma unroll
    for (int mm = 0; mm < 4; ++mm) {
        int m = half * 4 + mm;
        size_t o = (size_t)t * 1024 + m * 128 + r0;
        preQ[o] = __float2bfloat16(hq * gsh[0][m]);
        preK[o] = __float2bfloat16(hk * gsh[1][m]);
        preV[o] = __float2bfloat16(hv * gsh[2][m]);
    }
}

// -------------------- Flash attention (MFMA) --------------------
#define LDK 68   // padded halfword stride for K/V/P LDS tiles

// Work-balanced dispatch: block c (c<256) gets qt=15-(c>>5); block c+256 gets
// qt=(c>>5). Under round-robin dispatch, c and c+256 co-reside on the same CU
// (256%8==0 preserves XCD and CU slot), so each CU hosts ~17 K-tile
// iterations total. Placement is a perf heuristic only — any assignment is
// correct.
__global__ __launch_bounds__(256) void flash_attn(const bf16* __restrict__ Q,
                                                  const bf16* __restrict__ K,
                                                  const bf16* __restrict__ V,
                                                  bf16* __restrict__ out) {
    const int bx = blockIdx.x;
    const int qt = (bx < 256) ? (15 - (bx >> 5)) : ((bx - 256) >> 5);
    const int bh = bx & 31;
    const int b = bh >> 4;
    const int h = bh & 15;
    const int tid = threadIdx.x;
    const int wave = tid >> 6;
    const int lane = tid & 63;
    const int quad = lane >> 4;
    const int l15 = lane & 15;

    __shared__ short Ks[64 * LDK];        // Ks[kr][dh]
    __shared__ short Vt[64 * LDK];        // Vt[dh][kr]
    __shared__ short Ps[4 * 16 * LDK];    // per-wave P[m][kr]

    const int q_row = qt * 64 + wave * 16 + l15;
    const bf16* qptr = Q + (size_t)(b * SS + q_row) * DD + h * DH + quad * 8;
    short8 aq0 = *(const short8*)qptr;
    short8 aq1 = *(const short8*)(qptr + 32);

    float m_r[4], l_r[4];
    f32x4 o[4];
#pragma unroll
    for (int r = 0; r < 4; ++r) { m_r[r] = -3.0e38f; l_r[r] = 0.f; }
#pragma unroll
    for (int c = 0; c < 4; ++c) o[c] = (f32x4)0.f;

    const float scale = 0.125f;

    for (int kt = 0; kt <= qt; ++kt) {
        const int kt0 = kt * 64;
        __syncthreads();
        {
            const int kr = tid >> 2;
            const int dhb = (tid & 3) * 16;
            const bf16* src = K + (size_t)(b * SS + kt0 + kr) * DD + h * DH + dhb;
            short4v v0 = *(const short4v*)(src);
            short4v v1 = *(const short4v*)(src + 4);
            short4v v2 = *(const short4v*)(src + 8);
            short4v v3 = *(const short4v*)(src + 12);
            short* dst = &Ks[kr * LDK + dhb];
            *(short4v*)(dst) = v0;
            *(short4v*)(dst + 4) = v1;
            *(short4v*)(dst + 8) = v2;
            *(short4v*)(dst + 12) = v3;
        }
        {
            const int krp = tid & 31;
            const int dhb = (tid >> 5) * 8;
            const bf16* s0 = V + (size_t)(b * SS + kt0 + 2 * krp) * DD + h * DH + dhb;
            short8 r0 = *(const short8*)s0;
            short8 r1 = *(const short8*)(s0 + DD);
#pragma unroll
            for (int i = 0; i < 8; ++i) {
                unsigned int pk = (unsigned short)r0[i] | ((unsigned int)(unsigned short)r1[i] << 16);
                *(unsigned int*)&Vt[(dhb + i) * LDK + 2 * krp] = pk;
            }
        }
        __syncthreads();

        f32x4 s[4];
#pragma unroll
        for (int c = 0; c < 4; ++c) {
            short8 bk0 = lds_load8(&Ks[(c * 16 + l15) * LDK + quad * 8]);
            short8 bk1 = lds_load8(&Ks[(c * 16 + l15) * LDK + 32 + quad * 8]);
            f32x4 acc = (f32x4)0.f;
            acc = __builtin_amdgcn_mfma_f32_16x16x32_bf16(aq0, bk0, acc, 0, 0, 0);
            acc = __builtin_amdgcn_mfma_f32_16x16x32_bf16(aq1, bk1, acc, 0, 0, 0);
            s[c] = acc;
        }

        const bool diag = (kt == qt);
#pragma unroll
        for (int c = 0; c < 4; ++c) {
#pragma unroll
            for (int r = 0; r < 4; ++r) {
                float v = s[c][r] * scale;
                if (diag) {
                    int row_rel = wave * 16 + quad * 4 + r;
                    int col_rel = c * 16 + l15;
                    if (col_rel > row_rel) v = -3.0e38f;
                }
                s[c][r] = v;
            }
        }

        float p[4][4];
        float alpha[4];
#pragma unroll
        for (int r = 0; r < 4; ++r) {
            float mx = fmaxf(fmaxf(s[0][r], s[1][r]), fmaxf(s[2][r], s[3][r]));
            mx = fmaxf(mx, __shfl_xor(mx, 1));
            mx = fmaxf(mx, __shfl_xor(mx, 2));
            mx = fmaxf(mx, __shfl_xor(mx, 4));
            mx = fmaxf(mx, __shfl_xor(mx, 8));
            float new_m = fmaxf(m_r[r], mx);
            alpha[r] = __expf(m_r[r] - new_m);
            float rs = 0.f;
#pragma unroll
            for (int c = 0; c < 4; ++c) {
                float e = __expf(s[c][r] - new_m);
                p[c][r] = e;
                rs += e;
            }
            rs += __shfl_xor(rs, 1);
            rs += __shfl_xor(rs, 2);
            rs += __shfl_xor(rs, 4);
            rs += __shfl_xor(rs, 8);
            l_r[r] = l_r[r] * alpha[r] + rs;
            m_r[r] = new_m;
        }
#pragma unroll
        for (int c = 0; c < 4; ++c)
#pragma unroll
            for (int r = 0; r < 4; ++r) o[c][r] *= alpha[r];

        // P: C-layout -> wave-private LDS slab -> A-layout (no barrier needed)
        short* pw = &Ps[wave * 16 * LDK];
#pragma unroll
        for (int c = 0; c < 4; ++c)
#pragma unroll
            for (int r = 0; r < 4; ++r) {
                bf16 hb = __float2bfloat16(p[c][r]);
                pw[(quad * 4 + r) * LDK + c * 16 + l15] = *(short*)&hb;
            }

        short8 ap0 = lds_load8(&pw[l15 * LDK + quad * 8]);
        short8 ap1 = lds_load8(&pw[l15 * LDK + 32 + quad * 8]);

#pragma unroll
        for (int c = 0; c < 4; ++c) {
            short8 bv0 = lds_load8(&Vt[(c * 16 + l15) * LDK + quad * 8]);
            short8 bv1 = lds_load8(&Vt[(c * 16 + l15) * LDK + 32 + quad * 8]);
            o[c] = __builtin_amdgcn_mfma_f32_16x16x32_bf16(ap0, bv0, o[c], 0, 0, 0);
            o[c] = __builtin_amdgcn_mfma_f32_16x16x32_bf16(ap1, bv1, o[c], 0, 0, 0);
        }
    }

#pragma unroll
    for (int c = 0; c < 4; ++c) {
#pragma unroll
        for (int r = 0; r < 4; ++r) {
            int row = qt * 64 + wave * 16 + quad * 4 + r;
            int col = c * 16 + l15;
            out[(size_t)(b * SS + row) * DD + h * DH + col] = __float2bfloat16(o[c][r] / l_r[r]);
        }
    }
}

extern "C" void kernel_launch(void* const* d_in, const int* in_sizes, int n_in,
                              void* d_out, int out_size, void* d_ws, size_t ws_size,
                              hipStream_t stream) {
    const float* x    = (const float*)d_in[0];
    const float* qk_f = (const float*)d_in[1];
    const float* qk_r = (const float*)d_in[2];
    const float* v_f  = (const float*)d_in[3];
    const float* v_r  = (const float*)d_in[4];
    const float* Wg_q = (const float*)d_in[5];
    const float* Wg_k = (const float*)d_in[6];
    const float* Wg_v = (const float*)d_in[7];
    const float* W_O  = (const float*)d_in[8];

    // Workspace epochs (peak 22 MiB <= proven 23.19 MiB).
    // ws:  0..4    xb      -> preQ      -> attnb
    //      4..8    wg_bt(4..5.5)+fbt head -> preK
    //      5.5..9.5 fbt    (dead after proj)
    //      8..12           -> Kb  (over dead fbt tail / logits head)
    //      9.5..12.5 logits (dead after gate_combine)
    //      12..16          -> Vb  (over dead logits tail)
    //      16..18 qkr_bt | 18..20 vr_bt | 20..22 wo_bt (stable)
    // d_out: allh [0..8 MiB] -> preV in-place over allh_v [4..8] -> Qb [0..4]
    //        -> final f32 out [0..8]
    char* w = (char*)d_ws;
    const size_t MB = 1 << 20;
    bf16* xb     = (bf16*)(w + 0);
    bf16* wg_bt  = (bf16*)(w + 4 * MB);
    bf16* fbt    = (bf16*)(w + (size_t)(5.5 * MB));
    bf16* logits = (bf16*)(w + (size_t)(9.5 * MB));
    bf16* qkr_bt = (bf16*)(w + 16 * MB);
    bf16* vr_bt  = (bf16*)(w + 18 * MB);
    bf16* wo_bt  = (bf16*)(w + 20 * MB);
    bf16* preQ   = (bf16*)(w + 0);
    bf16* preK   = (bf16*)(w + 4 * MB);
    bf16* Kb     = (bf16*)(w + 8 * MB);
    bf16* Vb     = (bf16*)(w + 12 * MB);
    bf16* attnb  = (bf16*)(w + 0);
    bf16* allh   = (bf16*)d_out;              // [2][2048][1024] bf16 = 8 MiB
    bf16* preV   = allh + (size_t)NT * DD;    // in-place over allh_v
    bf16* Qb     = (bf16*)d_out;              // over dead allh_qk
    float* out   = (float*)d_out;

    // 1) convert/transpose all inputs to bf16 (weights -> Bt[N][K])
    ConvJobs J;
    J.src[0] = qk_f; J.dst[0] = fbt;              J.K[0] = 1024; J.R[0] = 128;  J.G[0] = 8;
    J.src[1] = v_f;  J.dst[1] = fbt + 1024*1024;  J.K[1] = 1024; J.R[1] = 128;  J.G[1] = 8;
    J.src[2] = qk_r; J.dst[2] = qkr_bt;           J.K[2] = 1024; J.R[2] = 1024; J.G[2] = 1;
    J.src[3] = v_r;  J.dst[3] = vr_bt;            J.K[3] = 1024; J.R[3] = 1024; J.G[3] = 1;
    J.src[4] = W_O;  J.dst[4] = wo_bt;            J.K[4] = 1024; J.R[4] = 1024; J.G[4] = 1;
    J.src[5] = Wg_q; J.dst[5] = wg_bt;            J.K[5] = 1024; J.R[5] = 256;  J.G[5] = 1;
    J.src[6] = Wg_k; J.dst[6] = wg_bt + 256*1024; J.K[6] = 1024; J.R[6] = 256;  J.G[6] = 1;
    J.src[7] = Wg_v; J.dst[7] = wg_bt + 2*256*1024; J.K[7] = 1024; J.R[7] = 256; J.G[7] = 1;
    J.src[8] = x;    J.dst[8] = xb;               J.K[8] = 0;    J.R[8] = 0;    J.G[8] = 0;
    int tiles[9] = {1024, 1024, 1024, 1024, 1024, 256, 256, 256, 512};
    int cum = 0;
    for (int i = 0; i < 9; ++i) { cum += tiles[i]; J.tEnd[i] = cum; }
    convert_kernel<<<cum, 256, 0, stream>>>(J);

    // 2) all projections in ONE launch (z=5): all_h(qk), all_h(v), 3 gate logits
    GemmZ Pp;
    Pp.A[0] = Pp.A[1] = Pp.A[2] = Pp.A[3] = Pp.A[4] = xb;
    Pp.Bt[0] = fbt;             Pp.Bt[1] = fbt + 1024*1024;
    Pp.Bt[2] = wg_bt;           Pp.Bt[3] = wg_bt + 256*1024;  Pp.Bt[4] = wg_bt + 2*256*1024;
    Pp.C[0] = allh;             Pp.C[1] = allh + (size_t)NT * DD;
    Pp.C[2] = logits;           Pp.C[3] = logits + (size_t)NT * NN;
    Pp.C[4] = logits + 2 * (size_t)NT * NN;
    Pp.N[0] = 1024; Pp.N[1] = 1024; Pp.N[2] = 256; Pp.N[3] = 256; Pp.N[4] = 256;
    mfma_gemm_z<bf16><<<dim3(8, 16, 5), 256, 0, stream>>>(Pp, DD);

    // 3) fused gates + combine + make_pre (preV in-place in d_out)
    gate_combine<<<NT, 256, 0, stream>>>(logits, allh, preQ, preK, preV);

    // 4) restore Q,K,V in ONE launch (z=3, 384 blocks)
    GemmZ Pr;
    Pr.A[0] = preQ; Pr.A[1] = preK; Pr.A[2] = preV;
    Pr.Bt[0] = qkr_bt; Pr.Bt[1] = qkr_bt; Pr.Bt[2] = vr_bt;
    Pr.C[0] = Qb; Pr.C[1] = Kb; Pr.C[2] = Vb;
    Pr.N[0] = Pr.N[1] = Pr.N[2] = 1024;
    Pr.A[3] = Pr.A[4] = nullptr; Pr.Bt[3] = Pr.Bt[4] = nullptr;
    Pr.C[3] = Pr.C[4] = nullptr; Pr.N[3] = Pr.N[4] = 0;
    mfma_gemm_z<bf16><<<dim3(8, 16, 3), 256, 0, stream>>>(Pr, DD);

    // 5) flash attention -> attnb (work-balanced 1-D grid)
    flash_attn<<<dim3(512), 256, 0, stream>>>(Qb, Kb, Vb, attnb);

    // 6) out = attnb @ W_O (f32 into d_out; 64x128 tiles -> 256 blocks)
    mfma_gemm_64<float><<<dim3(8, 32), 256, 0, stream>>>(attnb, wo_bt, out, DD, DD);
}

// Round 7
// 216.193 us; speedup vs baseline: 12.1550x; 1.0407x over previous
//
#include <hip/hip_runtime.h>
#include <hip/hip_bf16.h>

// Problem constants
#define BB 2
#define SS 1024
#define DD 1024
#define NH 16
#define DH 64
#define MM 8
#define RR 128
#define NN 256
#define NT (BB*SS)          // 2048 tokens

using bf16 = __hip_bfloat16;

typedef __attribute__((ext_vector_type(8))) short short8;   // 8 bf16 (4 VGPRs) MFMA A/B frag
typedef __attribute__((ext_vector_type(4))) short short4v;  // 8-byte unit
typedef __attribute__((ext_vector_type(4))) float f32x4;    // MFMA C/D frag

__device__ __forceinline__ void stf(float* p, size_t i, float v) { p[i] = v; }
__device__ __forceinline__ void stf(bf16* p, size_t i, float v) { p[i] = __float2bfloat16(v); }

// async 16B global->LDS (lane i lands at ldsbase + i*16; ldsbase wave-uniform)
#define GLD16(g, l) __builtin_amdgcn_global_load_lds( \
    (const __attribute__((address_space(1))) void*)(g), \
    (__attribute__((address_space(3))) void*)(l), 16, 0, 0)

// Load 8 bf16 (as shorts) from LDS via two 8B reads (base only 8B-aligned).
__device__ __forceinline__ short8 lds_load8(const short* p) {
    short4v a = *(const short4v*)p;
    short4v b = *(const short4v*)(p + 4);
    short8 r;
    r[0] = a[0]; r[1] = a[1]; r[2] = a[2]; r[3] = a[3];
    r[4] = b[0]; r[5] = b[1]; r[6] = b[2]; r[7] = b[3];
    return r;
}

// ---------------- MFMA GEMM, 64x128 tile, z-batched ----------------
// C[M,N] = A[M,K] @ Bt[N,K]^T, bf16 K-major. 4 waves (2x2), wave = 32x64
// (2x4 16x16x32 frags). Per-z A/Bt/C/N with early-exit for n0 >= N[z].
// TAG only distinguishes kernel names in profiles (proj vs restore).
struct GemmZ {
    const bf16* A[5];
    const bf16* Bt[5];
    void* C[5];
    int N[5];
};

template <typename TC, int TAG>
__global__ __launch_bounds__(256) void mfma_gemm_64z(GemmZ P, int Kdim) {
    const int z = blockIdx.z;
    const int Nz = P.N[z];
    const int n0 = blockIdx.x * 128;
    if (n0 >= Nz) return;
    const bf16* __restrict__ A  = P.A[z];
    const bf16* __restrict__ Bt = P.Bt[z];
    TC* __restrict__ C = (TC*)P.C[z];

    const int tid = threadIdx.x;
    const int wave = tid >> 6, lane = tid & 63;
    const int quad = lane >> 4, l15 = lane & 15;
    const int wr = wave >> 1, wc = wave & 1;
    const int m0 = blockIdx.y * 64;

    __shared__ bf16 As[64 * 32];
    __shared__ bf16 Bs[128 * 32];

    f32x4 acc[2][4];
#pragma unroll
    for (int i = 0; i < 2; ++i)
#pragma unroll
        for (int j = 0; j < 4; ++j) acc[i][j] = (f32x4)0.f;

    for (int k0 = 0; k0 < Kdim; k0 += 32) {
        __syncthreads();
        {   // A: 256 16B-chunks, one per thread
            const int L = wave * 64 + lane;
            const int row = L >> 2;
            const int gch = (L & 3) ^ ((row >> 1) & 3);   // XOR swizzle
            GLD16(A + (size_t)(m0 + row) * Kdim + k0 + gch * 8, &As[(wave * 64) * 8]);
        }
#pragma unroll
        for (int i = 0; i < 2; ++i) {   // B: 512 chunks
            const int L = i * 256 + wave * 64 + lane;
            const int row = L >> 2;
            const int gch = (L & 3) ^ ((row >> 1) & 3);
            GLD16(Bt + (size_t)(n0 + row) * Kdim + k0 + gch * 8, &Bs[(i * 256 + wave * 64) * 8]);
        }
        __syncthreads();   // vmcnt(0): tiles resident

        short8 aF[2], bF[4];
#pragma unroll
        for (int bi = 0; bi < 2; ++bi) {
            int m = wr * 32 + bi * 16 + l15;
            aF[bi] = *(const short8*)&As[(m * 4 + (quad ^ ((m >> 1) & 3))) * 8];
        }
#pragma unroll
        for (int bj = 0; bj < 4; ++bj) {
            int n = wc * 64 + bj * 16 + l15;
            bF[bj] = *(const short8*)&Bs[(n * 4 + (quad ^ ((n >> 1) & 3))) * 8];
        }
#pragma unroll
        for (int bi = 0; bi < 2; ++bi)
#pragma unroll
            for (int bj = 0; bj < 4; ++bj)
                acc[bi][bj] = __builtin_amdgcn_mfma_f32_16x16x32_bf16(aF[bi], bF[bj], acc[bi][bj], 0, 0, 0);
    }

#pragma unroll
    for (int bi = 0; bi < 2; ++bi)
#pragma unroll
        for (int bj = 0; bj < 4; ++bj)
#pragma unroll
            for (int r = 0; r < 4; ++r) {
                int row = m0 + wr * 32 + bi * 16 + quad * 4 + r;
                int col = n0 + wc * 64 + bj * 16 + l15;
                stf(C, (size_t)row * Nz + col, acc[bi][bj][r]);
            }
}

// ---------------- MFMA GEMM, 64x128 tile, single job (W_O) ----------------
template <typename TC>
__global__ __launch_bounds__(256) void mfma_gemm_64(
    const bf16* __restrict__ A, const bf16* __restrict__ Bt, TC* __restrict__ C,
    int Kdim, int Ndim) {
    const int tid = threadIdx.x;
    const int wave = tid >> 6, lane = tid & 63;
    const int quad = lane >> 4, l15 = lane & 15;
    const int wr = wave >> 1, wc = wave & 1;
    const int m0 = blockIdx.y * 64;
    const int n0 = blockIdx.x * 128;

    __shared__ bf16 As[64 * 32];
    __shared__ bf16 Bs[128 * 32];

    f32x4 acc[2][4];
#pragma unroll
    for (int i = 0; i < 2; ++i)
#pragma unroll
        for (int j = 0; j < 4; ++j) acc[i][j] = (f32x4)0.f;

    for (int k0 = 0; k0 < Kdim; k0 += 32) {
        __syncthreads();
        {
            const int L = wave * 64 + lane;
            const int row = L >> 2;
            const int gch = (L & 3) ^ ((row >> 1) & 3);
            GLD16(A + (size_t)(m0 + row) * Kdim + k0 + gch * 8, &As[(wave * 64) * 8]);
        }
#pragma unroll
        for (int i = 0; i < 2; ++i) {
            const int L = i * 256 + wave * 64 + lane;
            const int row = L >> 2;
            const int gch = (L & 3) ^ ((row >> 1) & 3);
            GLD16(Bt + (size_t)(n0 + row) * Kdim + k0 + gch * 8, &Bs[(i * 256 + wave * 64) * 8]);
        }
        __syncthreads();

        short8 aF[2], bF[4];
#pragma unroll
        for (int bi = 0; bi < 2; ++bi) {
            int m = wr * 32 + bi * 16 + l15;
            aF[bi] = *(const short8*)&As[(m * 4 + (quad ^ ((m >> 1) & 3))) * 8];
        }
#pragma unroll
        for (int bj = 0; bj < 4; ++bj) {
            int n = wc * 64 + bj * 16 + l15;
            bF[bj] = *(const short8*)&Bs[(n * 4 + (quad ^ ((n >> 1) & 3))) * 8];
        }
#pragma unroll
        for (int bi = 0; bi < 2; ++bi)
#pragma unroll
            for (int bj = 0; bj < 4; ++bj)
                acc[bi][bj] = __builtin_amdgcn_mfma_f32_16x16x32_bf16(aF[bi], bF[bj], acc[bi][bj], 0, 0, 0);
    }

#pragma unroll
    for (int bi = 0; bi < 2; ++bi)
#pragma unroll
        for (int bj = 0; bj < 4; ++bj)
#pragma unroll
            for (int r = 0; r < 4; ++r) {
                int row = m0 + wr * 32 + bi * 16 + quad * 4 + r;
                int col = n0 + wc * 64 + bj * 16 + l15;
                stf(C, (size_t)row * Ndim + col, acc[bi][bj][r]);
            }
}

// ---------------- fused convert/transpose (f32 -> bf16) ----------------
struct ConvJobs {
    const float* src[9];
    bf16* dst[9];
    int K[9], R[9], G[9];
    int tEnd[9];   // cumulative tile counts
};

__global__ void convert_kernel(ConvJobs J) {
    __shared__ float tile[32][33];
    const int b = blockIdx.x;
    int j = 0;
    while (j < 8 && b >= J.tEnd[j]) ++j;
    const int local = b - (j > 0 ? J.tEnd[j - 1] : 0);
    const float* src = J.src[j];
    bf16* dst = J.dst[j];
    const int tid = threadIdx.x;

    if (J.G[j] == 0) {
        size_t base = (size_t)local * 4096 + (size_t)tid * 16;
        const float4* s4 = (const float4*)(src + base);
        short* d = (short*)(dst + base);
#pragma unroll
        for (int c = 0; c < 4; ++c) {
            float4 v = s4[c];
            short4v o;
            bf16 t0 = __float2bfloat16(v.x); o[0] = *(short*)&t0;
            bf16 t1 = __float2bfloat16(v.y); o[1] = *(short*)&t1;
            bf16 t2 = __float2bfloat16(v.z); o[2] = *(short*)&t2;
            bf16 t3 = __float2bfloat16(v.w); o[3] = *(short*)&t3;
            *(short4v*)(d + c * 4) = o;
        }
    } else {
        const int Kj = J.K[j], Rj = J.R[j];
        const int Rb = Rj >> 5, Kb = Kj >> 5;
        const int perG = Kb * Rb;
        const int g = local / perG;
        const int rem = local - g * perG;
        const int kb = rem / Rb, rb = rem - kb * Rb;
        const int tx = tid & 31, ty0 = tid >> 5;
        const float* s = src + ((size_t)(g * Kj + kb * 32) * Rj) + rb * 32 + tx;
#pragma unroll
        for (int p = 0; p < 4; ++p)
            tile[ty0 + p * 8][tx] = s[(size_t)(ty0 + p * 8) * Rj];
        __syncthreads();
        bf16* dd = dst + ((size_t)(g * Rj + rb * 32) * Kj) + kb * 32 + tx;
#pragma unroll
        for (int p = 0; p < 4; ++p)
            dd[(size_t)(ty0 + p * 8) * Kj] = __float2bfloat16(tile[tx][ty0 + p * 8]);
    }
}

// ---------------- fused gates + combine + make_pre ----------------
__global__ void gate_combine(const bf16* __restrict__ logitsAll,
                             const bf16* __restrict__ allh,
                             bf16* __restrict__ preQ, bf16* __restrict__ preK,
                             bf16* __restrict__ preV) {
    const int t = blockIdx.x;
    const int n = threadIdx.x;   // 256
    __shared__ float red[256];
    __shared__ float probs[256];
    __shared__ float gsh[3][8];

#pragma unroll
    for (int z = 0; z < 3; ++z) {
        float v = __bfloat162float(logitsAll[(size_t)z * NT * NN + (size_t)t * NN + n]);
        red[n] = v;
        __syncthreads();
        for (int s = 128; s > 0; s >>= 1) {
            if (n < s) red[n] = fmaxf(red[n], red[n + s]);
            __syncthreads();
        }
        float mx = red[0];
        __syncthreads();
        float e = expf(v - mx);
        probs[n] = e;
        red[n] = e;
        __syncthreads();
        for (int s = 128; s > 0; s >>= 1) {
            if (n < s) red[n] += red[n + s];
            __syncthreads();
        }
        float denom = red[0];
        __syncthreads();
        if (n < 8) {
            float s = 0.f;
#pragma unroll
            for (int i = 0; i < 32; ++i) s += probs[n * 32 + i];
            red[n] = s / denom;
        }
        __syncthreads();
        if (n == 0) {
            float tot = 0.f;
#pragma unroll
            for (int m = 0; m < 8; ++m) tot += red[m];
            float inv = 1.0f / (tot + 1e-8f);
#pragma unroll
            for (int m = 0; m < 8; ++m) gsh[z][m] = red[m] * inv;
        }
        __syncthreads();
    }

    const int r0 = n & 127;
    const int half = n >> 7;
    const bf16* src_qk = allh + (size_t)t * 1024;
    const bf16* src_v  = allh + (size_t)NT * DD + (size_t)t * 1024;
    float hq = 0.f, hk = 0.f, hv = 0.f;
#pragma unroll
    for (int m = 0; m < 8; ++m) {
        float aqk = __bfloat162float(src_qk[m * 128 + r0]);
        float av  = __bfloat162float(src_v[m * 128 + r0]);
        hq += aqk * gsh[0][m];
        hk += aqk * gsh[1][m];
        hv += av  * gsh[2][m];
    }
    __syncthreads();   // all allh_v reads complete before in-place preV writes
#pragma unroll
    for (int mm = 0; mm < 4; ++mm) {
        int m = half * 4 + mm;
        size_t o = (size_t)t * 1024 + m * 128 + r0;
        preQ[o] = __float2bfloat16(hq * gsh[0][m]);
        preK[o] = __float2bfloat16(hk * gsh[1][m]);
        preV[o] = __float2bfloat16(hv * gsh[2][m]);
    }
}

// -------------------- Flash attention, split-kt (MFMA) --------------------
// Each (b,h,qt) is computed by TWO blocks: half0 kt in [0,h0), half1 [h0,qt+1)
// with h0 = ceil((qt+1)/2). Critical path <= 8 K-tile iterations. Partials
// (unnormalized O f32, m, l) go to workspace; attn_combine merges.
// Dispatch pairing: c<512 -> half0 of qt=15-(c>>5); c>=512 -> half1 of
// qt=(c-512)>>5 (heavy half0 co-resident with light half1 per CU).
#define LDK 68   // padded halfword stride for K/V/P LDS tiles

__global__ __launch_bounds__(256) void flash_attn_split(
    const bf16* __restrict__ Q, const bf16* __restrict__ K,
    const bf16* __restrict__ V, float* __restrict__ Opart,
    float* __restrict__ ml) {
    const int bx = blockIdx.x;
    const int c = bx & 511;
    const int second = bx >> 9;
    const int qt = second ? (c >> 5) : (15 - (c >> 5));
    const int half = second;
    const int bh = c & 31;
    const int b = bh >> 4;
    const int h = bh & 15;
    const int h0 = (qt + 2) >> 1;
    const int kt_lo = half ? h0 : 0;
    const int kt_hi = half ? (qt + 1) : h0;

    const int tid = threadIdx.x;
    const int wave = tid >> 6;
    const int lane = tid & 63;
    const int quad = lane >> 4;
    const int l15 = lane & 15;

    __shared__ short Ks[64 * LDK];        // Ks[kr][dh]
    __shared__ short Vt[64 * LDK];        // Vt[dh][kr]
    __shared__ short Ps[4 * 16 * LDK];    // per-wave P[m][kr]

    const int q_row = qt * 64 + wave * 16 + l15;
    const bf16* qptr = Q + (size_t)(b * SS + q_row) * DD + h * DH + quad * 8;
    short8 aq0 = *(const short8*)qptr;
    short8 aq1 = *(const short8*)(qptr + 32);

    float m_r[4], l_r[4];
    f32x4 o[4];
#pragma unroll
    for (int r = 0; r < 4; ++r) { m_r[r] = -3.0e38f; l_r[r] = 0.f; }
#pragma unroll
    for (int cc = 0; cc < 4; ++cc) o[cc] = (f32x4)0.f;

    const float scale = 0.125f;

    for (int kt = kt_lo; kt < kt_hi; ++kt) {
        const int kt0 = kt * 64;
        __syncthreads();
        {
            const int kr = tid >> 2;
            const int dhb = (tid & 3) * 16;
            const bf16* src = K + (size_t)(b * SS + kt0 + kr) * DD + h * DH + dhb;
            short4v v0 = *(const short4v*)(src);
            short4v v1 = *(const short4v*)(src + 4);
            short4v v2 = *(const short4v*)(src + 8);
            short4v v3 = *(const short4v*)(src + 12);
            short* dst = &Ks[kr * LDK + dhb];
            *(short4v*)(dst) = v0;
            *(short4v*)(dst + 4) = v1;
            *(short4v*)(dst + 8) = v2;
            *(short4v*)(dst + 12) = v3;
        }
        {
            const int krp = tid & 31;
            const int dhb = (tid >> 5) * 8;
            const bf16* s0 = V + (size_t)(b * SS + kt0 + 2 * krp) * DD + h * DH + dhb;
            short8 r0 = *(const short8*)s0;
            short8 r1 = *(const short8*)(s0 + DD);
#pragma unroll
            for (int i = 0; i < 8; ++i) {
                unsigned int pk = (unsigned short)r0[i] | ((unsigned int)(unsigned short)r1[i] << 16);
                *(unsigned int*)&Vt[(dhb + i) * LDK + 2 * krp] = pk;
            }
        }
        __syncthreads();

        f32x4 s[4];
#pragma unroll
        for (int cc = 0; cc < 4; ++cc) {
            short8 bk0 = lds_load8(&Ks[(cc * 16 + l15) * LDK + quad * 8]);
            short8 bk1 = lds_load8(&Ks[(cc * 16 + l15) * LDK + 32 + quad * 8]);
            f32x4 acc = (f32x4)0.f;
            acc = __builtin_amdgcn_mfma_f32_16x16x32_bf16(aq0, bk0, acc, 0, 0, 0);
            acc = __builtin_amdgcn_mfma_f32_16x16x32_bf16(aq1, bk1, acc, 0, 0, 0);
            s[cc] = acc;
        }

        const bool diag = (kt == qt);
#pragma unroll
        for (int cc = 0; cc < 4; ++cc) {
#pragma unroll
            for (int r = 0; r < 4; ++r) {
                float v = s[cc][r] * scale;
                if (diag) {
                    int row_rel = wave * 16 + quad * 4 + r;
                    int col_rel = cc * 16 + l15;
                    if (col_rel > row_rel) v = -3.0e38f;
                }
                s[cc][r] = v;
            }
        }

        float p[4][4];
        float alpha[4];
#pragma unroll
        for (int r = 0; r < 4; ++r) {
            float mx = fmaxf(fmaxf(s[0][r], s[1][r]), fmaxf(s[2][r], s[3][r]));
            mx = fmaxf(mx, __shfl_xor(mx, 1));
            mx = fmaxf(mx, __shfl_xor(mx, 2));
            mx = fmaxf(mx, __shfl_xor(mx, 4));
            mx = fmaxf(mx, __shfl_xor(mx, 8));
            float new_m = fmaxf(m_r[r], mx);
            alpha[r] = __expf(m_r[r] - new_m);
            float rs = 0.f;
#pragma unroll
            for (int cc = 0; cc < 4; ++cc) {
                float e = __expf(s[cc][r] - new_m);
                p[cc][r] = e;
                rs += e;
            }
            rs += __shfl_xor(rs, 1);
            rs += __shfl_xor(rs, 2);
            rs += __shfl_xor(rs, 4);
            rs += __shfl_xor(rs, 8);
            l_r[r] = l_r[r] * alpha[r] + rs;
            m_r[r] = new_m;
        }
#pragma unroll
        for (int cc = 0; cc < 4; ++cc)
#pragma unroll
            for (int r = 0; r < 4; ++r) o[cc][r] *= alpha[r];

        // P: C-layout -> wave-private LDS slab -> A-layout (no barrier needed)
        short* pw = &Ps[wave * 16 * LDK];
#pragma unroll
        for (int cc = 0; cc < 4; ++cc)
#pragma unroll
            for (int r = 0; r < 4; ++r) {
                bf16 hb = __float2bfloat16(p[cc][r]);
                pw[(quad * 4 + r) * LDK + cc * 16 + l15] = *(short*)&hb;
            }

        short8 ap0 = lds_load8(&pw[l15 * LDK + quad * 8]);
        short8 ap1 = lds_load8(&pw[l15 * LDK + 32 + quad * 8]);

#pragma unroll
        for (int cc = 0; cc < 4; ++cc) {
            short8 bv0 = lds_load8(&Vt[(cc * 16 + l15) * LDK + quad * 8]);
            short8 bv1 = lds_load8(&Vt[(cc * 16 + l15) * LDK + 32 + quad * 8]);
            o[cc] = __builtin_amdgcn_mfma_f32_16x16x32_bf16(ap0, bv0, o[cc], 0, 0, 0);
            o[cc] = __builtin_amdgcn_mfma_f32_16x16x32_bf16(ap1, bv1, o[cc], 0, 0, 0);
        }
    }

    // ---- write partials (unnormalized O, m, l) ----
    const int idx = (half * 32 + bh) * 16 + qt;
    float* ob = Opart + (size_t)idx * 4096;
#pragma unroll
    for (int cc = 0; cc < 4; ++cc)
#pragma unroll
        for (int r = 0; r < 4; ++r) {
            int row = wave * 16 + quad * 4 + r;
            ob[row * 64 + cc * 16 + l15] = o[cc][r];
        }
    if (l15 == 0) {
#pragma unroll
        for (int r = 0; r < 4; ++r) {
            int row = wave * 16 + quad * 4 + r;
            ml[(size_t)idx * 128 + row] = m_r[r];
            ml[(size_t)idx * 128 + 64 + row] = l_r[r];
        }
    }
}

// Merge the two kt-halves: out = (O0*w0 + O1*w1) / (l0*w0 + l1*w1),
// w_i = exp(m_i - max(m0,m1)). Empty half (m=-3e38, l=0) -> weight 0.
__global__ void attn_combine(const float* __restrict__ Opart,
                             const float* __restrict__ ml,
                             bf16* __restrict__ out) {
    const int bidx = blockIdx.x;       // 512 = bh*16 + qt
    const int bh = bidx >> 4;
    const int qt = bidx & 15;
    const int b = bh >> 4;
    const int h = bh & 15;
    const int tid = threadIdx.x;       // 256
    const int row = tid >> 2;
    const int cg = tid & 3;

    const int p0 = bh * 16 + qt;
    const int p1 = 512 + bh * 16 + qt;
    float m0 = ml[(size_t)p0 * 128 + row], l0 = ml[(size_t)p0 * 128 + 64 + row];
    float m1 = ml[(size_t)p1 * 128 + row], l1 = ml[(size_t)p1 * 128 + 64 + row];
    float ms = fmaxf(m0, m1);
    float w0 = __expf(m0 - ms), w1 = __expf(m1 - ms);
    float inv = 1.0f / (l0 * w0 + l1 * w1);

    const float* o0 = Opart + (size_t)p0 * 4096 + row * 64 + cg * 16;
    const float* o1 = Opart + (size_t)p1 * 4096 + row * 64 + cg * 16;
    short out16[16];
#pragma unroll
    for (int j = 0; j < 16; j += 4) {
        float4 a = *(const float4*)(o0 + j);
        float4 bb = *(const float4*)(o1 + j);
        float v0 = (a.x * w0 + bb.x * w1) * inv;
        float v1 = (a.y * w0 + bb.y * w1) * inv;
        float v2 = (a.z * w0 + bb.z * w1) * inv;
        float v3 = (a.w * w0 + bb.w * w1) * inv;
        bf16 t0 = __float2bfloat16(v0); out16[j] = *(short*)&t0;
        bf16 t1 = __float2bfloat16(v1); out16[j + 1] = *(short*)&t1;
        bf16 t2 = __float2bfloat16(v2); out16[j + 2] = *(short*)&t2;
        bf16 t3 = __float2bfloat16(v3); out16[j + 3] = *(short*)&t3;
    }
    short* dst = (short*)(out + (size_t)(b * SS + qt * 64 + row) * DD + h * DH + cg * 16);
    *(short8*)dst = *(short8*)&out16[0];
    *(short8*)(dst + 8) = *(short8*)&out16[8];
}

extern "C" void kernel_launch(void* const* d_in, const int* in_sizes, int n_in,
                              void* d_out, int out_size, void* d_ws, size_t ws_size,
                              hipStream_t stream) {
    const float* x    = (const float*)d_in[0];
    const float* qk_f = (const float*)d_in[1];
    const float* qk_r = (const float*)d_in[2];
    const float* v_f  = (const float*)d_in[3];
    const float* v_r  = (const float*)d_in[4];
    const float* Wg_q = (const float*)d_in[5];
    const float* Wg_k = (const float*)d_in[6];
    const float* Wg_v = (const float*)d_in[7];
    const float* W_O  = (const float*)d_in[8];

    // Workspace (ws_size proven 256 MiB by R6 fill WRITE_SIZE). Layout:
    //  0..4    xb      -> preQ      -> attnb
    //  4..8    wg_bt(4..5.5)+pad    -> preK
    //  5.5..9.5 fbt    (dead after proj)
    //  8..12           -> Kb
    //  9.5..12.5 logits (dead after gate_combine)
    //  12..16          -> Vb
    //  16..18 qkr_bt | 18..20 vr_bt | 20..22 wo_bt (stable)
    //  32..48 Opart (f32 partials) | 48..48.5 ml
    // d_out: allh [0..8 MiB] -> preV in-place over allh_v -> Qb [0..4] -> f32 out
    char* w = (char*)d_ws;
    const size_t MB = 1 << 20;
    bf16* xb     = (bf16*)(w + 0);
    bf16* wg_bt  = (bf16*)(w + 4 * MB);
    bf16* fbt    = (bf16*)(w + (size_t)(5.5 * MB));
    bf16* logits = (bf16*)(w + (size_t)(9.5 * MB));
    bf16* qkr_bt = (bf16*)(w + 16 * MB);
    bf16* vr_bt  = (bf16*)(w + 18 * MB);
    bf16* wo_bt  = (bf16*)(w + 20 * MB);
    bf16* preQ   = (bf16*)(w + 0);
    bf16* preK   = (bf16*)(w + 4 * MB);
    bf16* Kb     = (bf16*)(w + 8 * MB);
    bf16* Vb     = (bf16*)(w + 12 * MB);
    bf16* attnb  = (bf16*)(w + 0);
    float* Opart = (float*)(w + 32 * MB);     // 1024 * 4096 f32 = 16 MiB
    float* mlbuf = (float*)(w + 48 * MB);     // 1024 * 128 f32 = 0.5 MiB
    bf16* allh   = (bf16*)d_out;              // [2][2048][1024] bf16 = 8 MiB
    bf16* preV   = allh + (size_t)NT * DD;    // in-place over allh_v
    bf16* Qb     = (bf16*)d_out;              // over dead allh_qk
    float* out   = (float*)d_out;

    // 1) convert/transpose all inputs to bf16 (weights -> Bt[N][K])
    ConvJobs J;
    J.src[0] = qk_f; J.dst[0] = fbt;              J.K[0] = 1024; J.R[0] = 128;  J.G[0] = 8;
    J.src[1] = v_f;  J.dst[1] = fbt + 1024*1024;  J.K[1] = 1024; J.R[1] = 128;  J.G[1] = 8;
    J.src[2] = qk_r; J.dst[2] = qkr_bt;           J.K[2] = 1024; J.R[2] = 1024; J.G[2] = 1;
    J.src[3] = v_r;  J.dst[3] = vr_bt;            J.K[3] = 1024; J.R[3] = 1024; J.G[3] = 1;
    J.src[4] = W_O;  J.dst[4] = wo_bt;            J.K[4] = 1024; J.R[4] = 1024; J.G[4] = 1;
    J.src[5] = Wg_q; J.dst[5] = wg_bt;            J.K[5] = 1024; J.R[5] = 256;  J.G[5] = 1;
    J.src[6] = Wg_k; J.dst[6] = wg_bt + 256*1024; J.K[6] = 1024; J.R[6] = 256;  J.G[6] = 1;
    J.src[7] = Wg_v; J.dst[7] = wg_bt + 2*256*1024; J.K[7] = 1024; J.R[7] = 256; J.G[7] = 1;
    J.src[8] = x;    J.dst[8] = xb;               J.K[8] = 0;    J.R[8] = 0;    J.G[8] = 0;
    int tiles[9] = {1024, 1024, 1024, 1024, 1024, 256, 256, 256, 512};
    int cum = 0;
    for (int i = 0; i < 9; ++i) { cum += tiles[i]; J.tEnd[i] = cum; }
    convert_kernel<<<cum, 256, 0, stream>>>(J);

    // 2) all projections in ONE launch (z=5, 64x128 tiles -> 704 useful blocks)
    GemmZ Pp;
    Pp.A[0] = Pp.A[1] = Pp.A[2] = Pp.A[3] = Pp.A[4] = xb;
    Pp.Bt[0] = fbt;             Pp.Bt[1] = fbt + 1024*1024;
    Pp.Bt[2] = wg_bt;           Pp.Bt[3] = wg_bt + 256*1024;  Pp.Bt[4] = wg_bt + 2*256*1024;
    Pp.C[0] = allh;             Pp.C[1] = allh + (size_t)NT * DD;
    Pp.C[2] = logits;           Pp.C[3] = logits + (size_t)NT * NN;
    Pp.C[4] = logits + 2 * (size_t)NT * NN;
    Pp.N[0] = 1024; Pp.N[1] = 1024; Pp.N[2] = 256; Pp.N[3] = 256; Pp.N[4] = 256;
    mfma_gemm_64z<bf16, 0><<<dim3(8, 32, 5), 256, 0, stream>>>(Pp, DD);

    // 3) fused gates + combine + make_pre (preV in-place in d_out)
    gate_combine<<<NT, 256, 0, stream>>>(logits, allh, preQ, preK, preV);

    // 4) restore Q,K,V in ONE launch (z=3, 64x128 tiles -> 768 blocks)
    GemmZ Pr;
    Pr.A[0] = preQ; Pr.A[1] = preK; Pr.A[2] = preV;
    Pr.Bt[0] = qkr_bt; Pr.Bt[1] = qkr_bt; Pr.Bt[2] = vr_bt;
    Pr.C[0] = Qb; Pr.C[1] = Kb; Pr.C[2] = Vb;
    Pr.N[0] = Pr.N[1] = Pr.N[2] = 1024;
    Pr.A[3] = Pr.A[4] = nullptr; Pr.Bt[3] = Pr.Bt[4] = nullptr;
    Pr.C[3] = Pr.C[4] = nullptr; Pr.N[3] = Pr.N[4] = 0;
    mfma_gemm_64z<bf16, 1><<<dim3(8, 32, 3), 256, 0, stream>>>(Pr, DD);

    // 5) flash attention split-kt (1024 blocks, critical path 8 iters)
    flash_attn_split<<<dim3(1024), 256, 0, stream>>>(Qb, Kb, Vb, Opart, mlbuf);

    // 6) merge halves -> attnb
    attn_combine<<<dim3(512), 256, 0, stream>>>(Opart, mlbuf, attnb);

    // 7) out = attnb @ W_O (f32 into d_out; Qb dead after flash)
    mfma_gemm_64<float><<<dim3(8, 32), 256, 0, stream>>>(attnb, wo_bt, out, DD, DD);
}